// Round 4
// baseline (2075.237 us; speedup 1.0000x reference)
//
#include <hip/hip_runtime.h>
#include <cstdint>
#include <cstddef>

// Problem constants (B=2, M=32, D=64, T=2048, F=16, L=512, S=32768)
#define DAMP 0.9998f

// ---------------------------------------------------------------------------
// threefry2x32, JAX partitionable mode (default since JAX 0.5.0).
// key = jax.random.key(1) -> (k0=0, k1=1).
// Element j gets counter (hi32(j), lo32(j)) = (0, j) since n = 2^21 < 2^32.
// 32-bit output = bits1 ^ bits2 (XOR of the two output words).
// ---------------------------------------------------------------------------
__device__ __forceinline__ void threefry_0j(unsigned j, unsigned& o0, unsigned& o1) {
    unsigned x0 = 0u;        // hi counter + ks0(=0)
    unsigned x1 = j + 1u;    // lo counter + ks1(=1)
    const unsigned ks2 = 0x1BD11BDBu; // 0 ^ 1 ^ 0x1BD11BDA
#define TFR(r) { x0 += x1; x1 = (x1 << (r)) | (x1 >> (32 - (r))); x1 ^= x0; }
    TFR(13) TFR(15) TFR(26) TFR(6)
    x0 += 1u;   x1 += ks2 + 1u;
    TFR(17) TFR(29) TFR(16) TFR(24)
    x0 += ks2;  x1 += 0u + 2u;
    TFR(13) TFR(15) TFR(26) TFR(6)
    /*x0+=0*/   x1 += 1u + 3u;
    TFR(17) TFR(29) TFR(16) TFR(24)
    x0 += 1u;   x1 += ks2 + 4u;
    TFR(13) TFR(15) TFR(26) TFR(6)
    x0 += ks2;  x1 += 0u + 5u;
#undef TFR
    o0 = x0; o1 = x1;
}

__device__ __forceinline__ float noise_at(unsigned j) {
    unsigned o0, o1;
    threefry_0j(j, o0, o1);
    unsigned bits = o0 ^ o1;   // partitionable: XOR of both output words
    float u = __uint_as_float((bits >> 9) | 0x3F800000u) - 1.0f; // [0,1)
    return fmaxf(-1.0f, u * 2.0f - 1.0f);
}

// Dir(u) = sin(2049*pi*u/32768)/sin(pi*u/32768), Dir(0)=2049, period 32768.
__device__ __forceinline__ float dir_val(unsigned u) {
    if (u == 0u) return 2049.f;
    const float PIO = 9.58737992e-05f; // pi/32768
    unsigned y = (2049u * u) & 65535u;
    float sgn = 1.f;
    if (y >= 32768u) { y -= 32768u; sgn = -1.f; }
    unsigned yy = (y > 16384u) ? (32768u - y) : y;
    float sy = sgn * sinf((float)yy * PIO);
    unsigned uu = (u > 16384u) ? (32768u - u) : u;
    float su = sinf((float)uu * PIO);
    return sy / su;
}

// ---------------------------------------------------------------------------
// K1: sequential sim. 64 blocks (b*32+m), 64 threads (d).
// Writes displacement (=direction before pos update) and recording.
// ---------------------------------------------------------------------------
__global__ void sim_kernel(const float* __restrict__ forces, const float* __restrict__ hmod,
                           const float* __restrict__ home, const float* __restrict__ masses,
                           const float* __restrict__ tensions, const float* __restrict__ gains,
                           const float* __restrict__ mics, float* __restrict__ disp,
                           float* __restrict__ rec) {
    const int bm = blockIdx.x;
    const int m = bm & 31;
    const int d = threadIdx.x;
    const float k = tensions[m * 64 + d] / masses[m];
    const float gain = gains[m];
    const float mic = mics[m * 64 + d];
    const float hd = home[d];
    const size_t rowoff = ((size_t)bm * 64 + d) * 2048;
    const float* fp = forces + rowoff;
    const float* hp = hmod + rowoff;
    float* dpo = disp + rowoff;
    float* rp = rec + (size_t)bm * 2048;
    __shared__ float prod[64][65];
    float pos = 0.f, vel = 0.f;
    for (int t0 = 0; t0 < 2048; t0 += 64) {
        #pragma unroll 4
        for (int ts = 0; ts < 64; ++ts) {
            const int t = t0 + ts;
            const float f = fp[t];
            const float h = hd + hp[t];
            const float dir = h - pos;           // direction uses pos BEFORE update
            const float acc = f + k * dir;
            vel = (vel + acc) * DAMP;
            pos = pos + vel;
            dpo[t] = dir;
            const float x = vel * gain;
            const float e = __expf(2.f * x);
            const float th = 1.f - 2.f / (e + 1.f);  // tanh(x)
            prod[ts][d] = th * mic;
        }
        __syncthreads();
        float s = 0.f;
        #pragma unroll
        for (int j = 0; j < 64; ++j) s += prod[d][j];
        rp[t0 + d] = s;
        __syncthreads();
    }
}

// ---------------------------------------------------------------------------
// K2: fft_resample via per-phase circular convolution + abs*noise.
// up[bm, 16q+p] = |(1/8192) * sum_v Dir(16v+p)*rec[(q-v) mod 2048]| * noise
// grid (64 bm, 16 p), 512 threads, 4 q per thread. Dirichlet row computed
// in-block (no global table).
// ---------------------------------------------------------------------------
__global__ __launch_bounds__(512) void resample_kernel(const float* __restrict__ rec,
                                                       float* __restrict__ up) {
    const int bm = blockIdx.x;
    const int p = blockIdx.y;
    const int tid = threadIdx.x; // 512
    __shared__ __align__(16) float rec2[4096];
    __shared__ __align__(16) float dpl[2048];
    for (int i = tid; i < 2048; i += 512) {
        const float v = rec[(size_t)bm * 2048 + i];
        rec2[i] = v; rec2[i + 2048] = v;
        dpl[i] = dir_val(16u * (unsigned)i + (unsigned)p);
    }
    __syncthreads();
    const int qb = tid * 4;
    float a0 = 0.f, a1 = 0.f, a2 = 0.f, a3 = 0.f;
    const float4* f4r = (const float4*)rec2;
    const float4* f4d = (const float4*)dpl;
    for (int v0 = 0; v0 < 2048; v0 += 4) {
        const float4 dv = f4d[v0 >> 2];
        const int base = qb - v0 + 2044;           // multiple of 4, in [0,4088]
        const float4 wa = f4r[base >> 2];          // rec2[base..base+3]
        const float4 wb = f4r[(base >> 2) + 1];    // rec2[base+4..base+7]
        // a[j] += dv[i] * rec2[base + 4 + j - i]
        a0 += dv.x * wb.x; a0 += dv.y * wa.w; a0 += dv.z * wa.z; a0 += dv.w * wa.y;
        a1 += dv.x * wb.y; a1 += dv.y * wb.x; a1 += dv.z * wa.w; a1 += dv.w * wa.z;
        a2 += dv.x * wb.z; a2 += dv.y * wb.y; a2 += dv.z * wb.x; a2 += dv.w * wa.w;
        a3 += dv.x * wb.w; a3 += dv.y * wb.z; a3 += dv.z * wb.y; a3 += dv.w * wb.x;
    }
    const float av[4] = {a0, a1, a2, a3};
    const unsigned jbase = (unsigned)bm * 32768u;
    #pragma unroll
    for (int j = 0; j < 4; ++j) {
        const int s = 16 * (qb + j) + p;
        const float v = av[j] * (1.f / 8192.f);
        const float nz = noise_at(jbase + (unsigned)s);
        up[(size_t)bm * 32768 + s] = fabsf(v) * nz;
    }
}

// ---------------------------------------------------------------------------
// K3: hf[bm,s] = up[bm,s] + sum_f mix_interp[f,s] * sum_{l<512} fn[b,f,l]*up[bm,s-l]
// mixture (window of 131 t-values) computed in-block from disp + tofm;
// filter normalization computed in-block from raw filters.
// grid (16 s-tiles of 2048, 64 bm), 256 threads, 8 consecutive s per thread.
// ---------------------------------------------------------------------------
__global__ __launch_bounds__(256) void hf_kernel(const float* __restrict__ up,
                                                 const float* __restrict__ filters,
                                                 const float* __restrict__ disp,
                                                 const float* __restrict__ tofm,
                                                 float* __restrict__ hf) {
    const int tile = blockIdx.x;     // 0..15
    const int bm = blockIdx.y;       // 0..63
    const int b = bm >> 5;
    const int S0 = tile * 2048;
    const int tbase = tile * 128 - 1;
    const int tid = threadIdx.x;

    // 51.5 KB LDS, phase-aliased
    __shared__ __align__(16) float smem[12864];
    float* fnl  = smem;               // phase2: 16 x 512 normalized filters
    float* upw  = smem + 8192;        // phase2: up[S0-512 .. S0+2047] (2560)
    float* dspl = smem;               // phase1: 64 x 132 disp window
    float* tfl  = smem + 8448;        // phase1: 64 x 16 to_filter_mixture
    float (*mixl)[132] = (float (*)[132])(smem + 10752); // 16 x 132 mixture window
    __shared__ float nrm[16];

    // ---- phase 1: stage disp window + tofm; compute filter norms ----
    for (int i = tid; i < 1024; i += 256) tfl[i] = tofm[i];
    for (int i = tid; i < 64 * 131; i += 256) {
        const int d = i / 131, tt = i - d * 131;
        const int t = tbase + tt;
        dspl[d * 132 + tt] = (t >= 0 && t < 2048) ? disp[((size_t)bm * 64 + d) * 2048 + t] : 0.f;
    }
    {
        const int f = tid >> 4, l16 = tid & 15;
        const float* frow = filters + ((size_t)b * 16 + f) * 512;
        float part = 0.f;
        for (int l = l16; l < 512; l += 16) { const float v = frow[l]; part += v * v; }
        #pragma unroll
        for (int off = 8; off; off >>= 1) part += __shfl_xor(part, off);
        if (l16 == 0) nrm[f] = 1.f / (sqrtf(part) + 1e-8f);
    }
    __syncthreads();

    // ---- mixture window: mixl[f][tt] = sum_d dspl[d][tt] * tfl[d][f] ----
    for (int i = tid; i < 16 * 131; i += 256) {
        const int f = i / 131, tt = i - f * 131;
        float s = 0.f;
        #pragma unroll 8
        for (int d = 0; d < 64; ++d) s += dspl[d * 132 + tt] * tfl[d * 16 + f];
        mixl[f][tt] = s;
    }
    __syncthreads();

    // ---- phase 2: overwrite scratch with normalized filters + up window ----
    for (int i = tid; i < 8192; i += 256) fnl[i] = filters[(size_t)b * 8192 + i] * nrm[i >> 9];
    for (int i = tid; i < 2560; i += 256) {
        const int g = S0 - 512 + i;
        upw[i] = (g >= 0) ? up[(size_t)bm * 32768 + g] : 0.f;
    }
    __syncthreads();

    const int sb = tid * 8;
    const float4* f4u = (const float4*)upw;
    const float4* f4f = (const float4*)fnl;
    float hfa[8];
    #pragma unroll
    for (int j = 0; j < 8; ++j) hfa[j] = 0.f;

    for (int f = 0; f < 16; ++f) {
        float a[8];
        #pragma unroll
        for (int j = 0; j < 8; ++j) a[j] = 0.f;
        for (int l0 = 0; l0 < 512; l0 += 8) {
            const float4 c0 = f4f[f * 128 + (l0 >> 2)];
            const float4 c1 = f4f[f * 128 + (l0 >> 2) + 1];
            const int base = sb + 504 - l0;        // multiple of 4, in [0, 2040]
            const int bq = base >> 2;
            const float4 w0 = f4u[bq];
            const float4 w1 = f4u[bq + 1];
            const float4 w2 = f4u[bq + 2];
            const float4 w3 = f4u[bq + 3];
            const float w[16] = {w0.x, w0.y, w0.z, w0.w, w1.x, w1.y, w1.z, w1.w,
                                 w2.x, w2.y, w2.z, w2.w, w3.x, w3.y, w3.z, w3.w};
            const float cc[8] = {c0.x, c0.y, c0.z, c0.w, c1.x, c1.y, c1.z, c1.w};
            // upw[base + 8 + j - li] == up[S0 + sb + j - (l0+li)]
            #pragma unroll
            for (int li = 0; li < 8; ++li) {
                #pragma unroll
                for (int j = 0; j < 8; ++j) a[j] += cc[li] * w[8 + j - li];
            }
        }
        #pragma unroll
        for (int j = 0; j < 8; ++j) {
            const int s = S0 + sb + j;
            float posf = ((float)s + 0.5f) * 0.0625f - 0.5f;   // exact in fp32
            posf = fminf(fmaxf(posf, 0.f), 2047.f);
            const int i0 = (int)posf;
            const float wg = posf - (float)i0;
            const int i1 = min(i0 + 1, 2047);
            const float mv = mixl[f][i0 - tbase] * (1.f - wg) + mixl[f][i1 - tbase] * wg;
            hfa[j] += mv * a[j];
        }
    }
    float* o = hf + (size_t)bm * 32768 + S0 + sb;
    #pragma unroll
    for (int j = 0; j < 8; ++j) o[j] = hfa[j] + upw[sb + 512 + j];
}

// ---------------------------------------------------------------------------
// Launch
// ---------------------------------------------------------------------------
extern "C" void kernel_launch(void* const* d_in, const int* in_sizes, int n_in,
                              void* d_out, int out_size, void* d_ws, size_t ws_size,
                              hipStream_t stream) {
    const float* forces   = (const float*)d_in[0];   // (2,32,64,2048)
    const float* hmod     = (const float*)d_in[1];   // (2,32,64,2048)
    const float* filters  = (const float*)d_in[2];   // (2,16,512)
    const float* home     = (const float*)d_in[3];   // (1,1,64,1)
    const float* masses   = (const float*)d_in[4];   // (1,32,1)
    const float* tensions = (const float*)d_in[5];   // (1,32,64)
    const float* gains    = (const float*)d_in[6];   // (1,32,1)
    const float* mics     = (const float*)d_in[7];   // (1,32,64)
    const float* tofm     = (const float*)d_in[8];   // (64,16)

    float* out  = (float*)d_out;
    float* rec  = out;                  // 131072 = 2*32*2048
    float* disp = out + 131072;         // 8388608 = 2*32*64*2048
    float* hf   = out + 8519680;        // 2097152 = 2*32*32768

    float* up = (float*)d_ws;           // 2097152 floats = 8.39 MB total ws use

    sim_kernel<<<64, 64, 0, stream>>>(forces, hmod, home, masses, tensions, gains, mics, disp, rec);
    resample_kernel<<<dim3(64, 16), 512, 0, stream>>>(rec, up);
    hf_kernel<<<dim3(16, 64), 256, 0, stream>>>(up, filters, disp, tofm, hf);
}

// Round 5
// 1536.158 us; speedup vs baseline: 1.3509x; 1.3509x over previous
//
#include <hip/hip_runtime.h>
#include <cstdint>
#include <cstddef>

// Problem constants (B=2, M=32, D=64, T=2048, F=16, L=512, S=32768)
#define DAMP 0.9998f

// ---------------------------------------------------------------------------
// threefry2x32, JAX partitionable mode (default since JAX 0.5.0).
// key = jax.random.key(1) -> (k0=0, k1=1).
// Element j gets counter (hi32(j), lo32(j)) = (0, j) since n = 2^21 < 2^32.
// 32-bit output = o0 ^ o1 (XOR of the two output words).  [verified r4]
// ---------------------------------------------------------------------------
__device__ __forceinline__ void threefry_0j(unsigned j, unsigned& o0, unsigned& o1) {
    unsigned x0 = 0u;        // hi counter + ks0(=0)
    unsigned x1 = j + 1u;    // lo counter + ks1(=1)
    const unsigned ks2 = 0x1BD11BDBu; // 0 ^ 1 ^ 0x1BD11BDA
#define TFR(r) { x0 += x1; x1 = (x1 << (r)) | (x1 >> (32 - (r))); x1 ^= x0; }
    TFR(13) TFR(15) TFR(26) TFR(6)
    x0 += 1u;   x1 += ks2 + 1u;
    TFR(17) TFR(29) TFR(16) TFR(24)
    x0 += ks2;  x1 += 0u + 2u;
    TFR(13) TFR(15) TFR(26) TFR(6)
    /*x0+=0*/   x1 += 1u + 3u;
    TFR(17) TFR(29) TFR(16) TFR(24)
    x0 += 1u;   x1 += ks2 + 4u;
    TFR(13) TFR(15) TFR(26) TFR(6)
    x0 += ks2;  x1 += 0u + 5u;
#undef TFR
    o0 = x0; o1 = x1;
}

__device__ __forceinline__ float noise_at(unsigned j) {
    unsigned o0, o1;
    threefry_0j(j, o0, o1);
    unsigned bits = o0 ^ o1;   // partitionable: XOR of both output words
    float u = __uint_as_float((bits >> 9) | 0x3F800000u) - 1.0f; // [0,1)
    return fmaxf(-1.0f, u * 2.0f - 1.0f);
}

// Dir(u) = sin(2049*pi*u/32768)/sin(pi*u/32768), Dir(0)=2049, period 32768.
__device__ __forceinline__ float dir_val(unsigned u) {
    if (u == 0u) return 2049.f;
    const float PIO = 9.58737992e-05f; // pi/32768
    unsigned y = (2049u * u) & 65535u;
    float sgn = 1.f;
    if (y >= 32768u) { y -= 32768u; sgn = -1.f; }
    unsigned yy = (y > 16384u) ? (32768u - y) : y;
    float sy = sgn * sinf((float)yy * PIO);
    unsigned uu = (u > 16384u) ? (32768u - u) : u;
    float su = sinf((float)uu * PIO);
    return sy / su;
}

// ---------------------------------------------------------------------------
// K1: sequential sim. 64 blocks (b*32+m), 64 threads (d).
// Writes displacement (=direction before pos update) and recording.
// ---------------------------------------------------------------------------
__global__ void sim_kernel(const float* __restrict__ forces, const float* __restrict__ hmod,
                           const float* __restrict__ home, const float* __restrict__ masses,
                           const float* __restrict__ tensions, const float* __restrict__ gains,
                           const float* __restrict__ mics, float* __restrict__ disp,
                           float* __restrict__ rec) {
    const int bm = blockIdx.x;
    const int m = bm & 31;
    const int d = threadIdx.x;
    const float k = tensions[m * 64 + d] / masses[m];
    const float gain = gains[m];
    const float mic = mics[m * 64 + d];
    const float hd = home[d];
    const size_t rowoff = ((size_t)bm * 64 + d) * 2048;
    const float* fp = forces + rowoff;
    const float* hp = hmod + rowoff;
    float* dpo = disp + rowoff;
    float* rp = rec + (size_t)bm * 2048;
    __shared__ float prod[64][65];
    float pos = 0.f, vel = 0.f;
    for (int t0 = 0; t0 < 2048; t0 += 64) {
        #pragma unroll 4
        for (int ts = 0; ts < 64; ++ts) {
            const int t = t0 + ts;
            const float f = fp[t];
            const float h = hd + hp[t];
            const float dir = h - pos;           // direction uses pos BEFORE update
            const float acc = f + k * dir;
            vel = (vel + acc) * DAMP;
            pos = pos + vel;
            dpo[t] = dir;
            const float x = vel * gain;
            const float e = __expf(2.f * x);
            const float th = 1.f - 2.f / (e + 1.f);  // tanh(x)
            prod[ts][d] = th * mic;
        }
        __syncthreads();
        float s = 0.f;
        #pragma unroll
        for (int j = 0; j < 64; ++j) s += prod[d][j];
        rp[t0 + d] = s;
        __syncthreads();
    }
}

// ---------------------------------------------------------------------------
// K2: fft_resample via per-phase circular convolution + abs*noise.
// up[bm, 16q+p] = |(1/8192) * sum_v Dir(16v+p)*rec[(q-v) mod 2048]| * noise
// grid (64 bm, 16 p), 512 threads, 4 q per thread.
// ---------------------------------------------------------------------------
__global__ __launch_bounds__(512) void resample_kernel(const float* __restrict__ rec,
                                                       float* __restrict__ up) {
    const int bm = blockIdx.x;
    const int p = blockIdx.y;
    const int tid = threadIdx.x; // 512
    __shared__ __align__(16) float rec2[4096];
    __shared__ __align__(16) float dpl[2048];
    for (int i = tid; i < 2048; i += 512) {
        const float v = rec[(size_t)bm * 2048 + i];
        rec2[i] = v; rec2[i + 2048] = v;
        dpl[i] = dir_val(16u * (unsigned)i + (unsigned)p);
    }
    __syncthreads();
    const int qb = tid * 4;
    float a0 = 0.f, a1 = 0.f, a2 = 0.f, a3 = 0.f;
    const float4* f4r = (const float4*)rec2;
    const float4* f4d = (const float4*)dpl;
    for (int v0 = 0; v0 < 2048; v0 += 4) {
        const float4 dv = f4d[v0 >> 2];
        const int base = qb - v0 + 2044;           // multiple of 4, in [0,4088]
        const float4 wa = f4r[base >> 2];          // rec2[base..base+3]
        const float4 wb = f4r[(base >> 2) + 1];    // rec2[base+4..base+7]
        // a[j] += dv[i] * rec2[base + 4 + j - i]
        a0 += dv.x * wb.x; a0 += dv.y * wa.w; a0 += dv.z * wa.z; a0 += dv.w * wa.y;
        a1 += dv.x * wb.y; a1 += dv.y * wb.x; a1 += dv.z * wa.w; a1 += dv.w * wa.z;
        a2 += dv.x * wb.z; a2 += dv.y * wb.y; a2 += dv.z * wb.x; a2 += dv.w * wa.w;
        a3 += dv.x * wb.w; a3 += dv.y * wb.z; a3 += dv.z * wb.y; a3 += dv.w * wb.x;
    }
    const float av[4] = {a0, a1, a2, a3};
    const unsigned jbase = (unsigned)bm * 32768u;
    #pragma unroll
    for (int j = 0; j < 4; ++j) {
        const int s = 16 * (qb + j) + p;
        const float v = av[j] * (1.f / 8192.f);
        const float nz = noise_at(jbase + (unsigned)s);
        up[(size_t)bm * 32768 + s] = fabsf(v) * nz;
    }
}

// ---------------------------------------------------------------------------
// K3: hf[bm,s] = up[bm,s] + sum_f mix_interp[f,s] * sum_{l<512} fn[b,f,l]*up[bm,s-l]
// Conflict-free layout: thread t owns s = S0+4t+j and s = S0+1024+4t+j (j=0..3),
// so all upw LDS reads are float4 at word offset 4t+c — contiguous across the
// wave (16B/lane stride, the optimal pattern). Lag window via register pipeline.
// grid (16 s-tiles of 2048, 64 bm), 256 threads.
// ---------------------------------------------------------------------------
__global__ __launch_bounds__(256) void hf_kernel(const float* __restrict__ up,
                                                 const float* __restrict__ filters,
                                                 const float* __restrict__ disp,
                                                 const float* __restrict__ tofm,
                                                 float* __restrict__ hf) {
    const int tile = blockIdx.x;     // 0..15
    const int bm = blockIdx.y;       // 0..63
    const int b = bm >> 5;
    const int S0 = tile * 2048;
    const int tbase = tile * 128 - 1;
    const int tid = threadIdx.x;

    // 51.5 KB LDS, phase-aliased
    __shared__ __align__(16) float smem[12864];
    float* fnl  = smem;               // phase2: 16 x 512 normalized filters
    float* upw  = smem + 8192;        // phase2: up[S0-512 .. S0+2047] (2560)
    float* dspl = smem;               // phase1: 64 x 132 disp window
    float* tfl  = smem + 8448;        // phase1: 64 x 16 to_filter_mixture
    float (*mixl)[132] = (float (*)[132])(smem + 10752); // 16 x 132 mixture window
    __shared__ float nrm[16];

    // ---- phase 1: stage disp window + tofm; compute filter norms ----
    for (int i = tid; i < 1024; i += 256) tfl[i] = tofm[i];
    for (int i = tid; i < 64 * 131; i += 256) {
        const int d = i / 131, tt = i - d * 131;
        const int t = tbase + tt;
        dspl[d * 132 + tt] = (t >= 0 && t < 2048) ? disp[((size_t)bm * 64 + d) * 2048 + t] : 0.f;
    }
    {
        const int f = tid >> 4, l16 = tid & 15;
        const float* frow = filters + ((size_t)b * 16 + f) * 512;
        float part = 0.f;
        for (int l = l16; l < 512; l += 16) { const float v = frow[l]; part += v * v; }
        #pragma unroll
        for (int off = 8; off; off >>= 1) part += __shfl_xor(part, off);
        if (l16 == 0) nrm[f] = 1.f / (sqrtf(part) + 1e-8f);
    }
    __syncthreads();

    // ---- mixture window: mixl[f][tt] = sum_d dspl[d][tt] * tfl[d][f] ----
    for (int i = tid; i < 16 * 131; i += 256) {
        const int f = i / 131, tt = i - f * 131;
        float s = 0.f;
        #pragma unroll 8
        for (int d = 0; d < 64; ++d) s += dspl[d * 132 + tt] * tfl[d * 16 + f];
        mixl[f][tt] = s;
    }
    __syncthreads();

    // ---- phase 2: overwrite scratch with normalized filters + up window ----
    for (int i = tid; i < 8192; i += 256) fnl[i] = filters[(size_t)b * 8192 + i] * nrm[i >> 9];
    for (int i = tid; i < 2560; i += 256) {
        const int g = S0 - 512 + i;
        upw[i] = (g >= 0) ? up[(size_t)bm * 32768 + g] : 0.f;
    }
    __syncthreads();

    const int t = tid;
    const float4* f4u = (const float4*)upw;
    const float4* f4f = (const float4*)fnl;
    float hfa[8];
    #pragma unroll
    for (int j = 0; j < 8; ++j) hfa[j] = 0.f;

    for (int f = 0; f < 16; ++f) {
        float a[8];
        #pragma unroll
        for (int j = 0; j < 8; ++j) a[j] = 0.f;
        const float4* fnrow = f4f + f * 128;
        // register pipeline: pX = upw4[idx-1], cX = upw4[idx]
        float4 pA = f4u[t];
        float4 pB = f4u[t + 256];
        for (int l0 = 508; l0 >= 0; l0 -= 4) {
            const int idx = t + ((512 - l0) >> 2);      // t+1 .. t+128
            const float4 cA = f4u[idx];
            const float4 cB = f4u[idx + 256];
            const float4 cc = fnrow[l0 >> 2];           // fn[f][l0..l0+3], broadcast
            // group A (s = S0+4t+j): a[j] += cc[li] * upw[r + j - li], r = 4t+512-l0
            a[0] += cc.x * cA.x; a[1] += cc.x * cA.y; a[2] += cc.x * cA.z; a[3] += cc.x * cA.w;
            a[0] += cc.y * pA.w; a[1] += cc.y * cA.x; a[2] += cc.y * cA.y; a[3] += cc.y * cA.z;
            a[0] += cc.z * pA.z; a[1] += cc.z * pA.w; a[2] += cc.z * cA.x; a[3] += cc.z * cA.y;
            a[0] += cc.w * pA.y; a[1] += cc.w * pA.z; a[2] += cc.w * pA.w; a[3] += cc.w * cA.x;
            // group B (s = S0+1024+4t+j)
            a[4] += cc.x * cB.x; a[5] += cc.x * cB.y; a[6] += cc.x * cB.z; a[7] += cc.x * cB.w;
            a[4] += cc.y * pB.w; a[5] += cc.y * cB.x; a[6] += cc.y * cB.y; a[7] += cc.y * cB.z;
            a[4] += cc.z * pB.z; a[5] += cc.z * pB.w; a[6] += cc.z * cB.x; a[7] += cc.z * cB.y;
            a[4] += cc.w * pB.y; a[5] += cc.w * pB.z; a[6] += cc.w * pB.w; a[7] += cc.w * cB.x;
            pA = cA; pB = cB;
        }
        // epilogue: hfa[g*4+j] += mix_interp(f, s) * a[g*4+j]
        #pragma unroll
        for (int g = 0; g < 2; ++g) {
            #pragma unroll
            for (int j = 0; j < 4; ++j) {
                const int s = S0 + g * 1024 + 4 * t + j;
                float posf = ((float)s + 0.5f) * 0.0625f - 0.5f;   // exact in fp32
                posf = fminf(fmaxf(posf, 0.f), 2047.f);
                const int i0 = (int)posf;
                const float wg = posf - (float)i0;
                const int i1 = min(i0 + 1, 2047);
                const float mv = mixl[f][i0 - tbase] * (1.f - wg) + mixl[f][i1 - tbase] * wg;
                hfa[g * 4 + j] += mv * a[g * 4 + j];
            }
        }
    }
    float* o = hf + (size_t)bm * 32768 + S0;
    #pragma unroll
    for (int g = 0; g < 2; ++g) {
        #pragma unroll
        for (int j = 0; j < 4; ++j) {
            const int x = g * 1024 + 4 * t + j;
            o[x] = hfa[g * 4 + j] + upw[x + 512];
        }
    }
}

// ---------------------------------------------------------------------------
// Launch
// ---------------------------------------------------------------------------
extern "C" void kernel_launch(void* const* d_in, const int* in_sizes, int n_in,
                              void* d_out, int out_size, void* d_ws, size_t ws_size,
                              hipStream_t stream) {
    const float* forces   = (const float*)d_in[0];   // (2,32,64,2048)
    const float* hmod     = (const float*)d_in[1];   // (2,32,64,2048)
    const float* filters  = (const float*)d_in[2];   // (2,16,512)
    const float* home     = (const float*)d_in[3];   // (1,1,64,1)
    const float* masses   = (const float*)d_in[4];   // (1,32,1)
    const float* tensions = (const float*)d_in[5];   // (1,32,64)
    const float* gains    = (const float*)d_in[6];   // (1,32,1)
    const float* mics     = (const float*)d_in[7];   // (1,32,64)
    const float* tofm     = (const float*)d_in[8];   // (64,16)

    float* out  = (float*)d_out;
    float* rec  = out;                  // 131072 = 2*32*2048
    float* disp = out + 131072;         // 8388608 = 2*32*64*2048
    float* hf   = out + 8519680;        // 2097152 = 2*32*32768

    float* up = (float*)d_ws;           // 2097152 floats = 8.39 MB total ws use

    sim_kernel<<<64, 64, 0, stream>>>(forces, hmod, home, masses, tensions, gains, mics, disp, rec);
    resample_kernel<<<dim3(64, 16), 512, 0, stream>>>(rec, up);
    hf_kernel<<<dim3(16, 64), 256, 0, stream>>>(up, filters, disp, tofm, hf);
}

// Round 6
// 654.429 us; speedup vs baseline: 3.1711x; 2.3473x over previous
//
#include <hip/hip_runtime.h>
#include <cstdint>
#include <cstddef>

// Problem constants (B=2, M=32, D=64, T=2048, F=16, L=512, S=32768)
#define DAMP 0.9998f

typedef __attribute__((ext_vector_type(8))) short bf16x8;
typedef __attribute__((ext_vector_type(4))) float f32x4;

__device__ __forceinline__ unsigned short f2bf(float x) {
    unsigned u = __float_as_uint(x);
    unsigned r = (u + 0x7FFFu + ((u >> 16) & 1u)) >> 16;   // RNE
    return (unsigned short)r;
}
__device__ __forceinline__ float bf2f(unsigned short v) {
    return __uint_as_float((unsigned)v << 16);
}

// ---------------------------------------------------------------------------
// threefry2x32, JAX partitionable mode. key=(0,1); counter (0, j); o0^o1.
// [verified r4]
// ---------------------------------------------------------------------------
__device__ __forceinline__ void threefry_0j(unsigned j, unsigned& o0, unsigned& o1) {
    unsigned x0 = 0u;
    unsigned x1 = j + 1u;
    const unsigned ks2 = 0x1BD11BDBu;
#define TFR(r) { x0 += x1; x1 = (x1 << (r)) | (x1 >> (32 - (r))); x1 ^= x0; }
    TFR(13) TFR(15) TFR(26) TFR(6)
    x0 += 1u;   x1 += ks2 + 1u;
    TFR(17) TFR(29) TFR(16) TFR(24)
    x0 += ks2;  x1 += 0u + 2u;
    TFR(13) TFR(15) TFR(26) TFR(6)
    /*x0+=0*/   x1 += 1u + 3u;
    TFR(17) TFR(29) TFR(16) TFR(24)
    x0 += 1u;   x1 += ks2 + 4u;
    TFR(13) TFR(15) TFR(26) TFR(6)
    x0 += ks2;  x1 += 0u + 5u;
#undef TFR
    o0 = x0; o1 = x1;
}

__device__ __forceinline__ float noise_at(unsigned j) {
    unsigned o0, o1;
    threefry_0j(j, o0, o1);
    unsigned bits = o0 ^ o1;
    float u = __uint_as_float((bits >> 9) | 0x3F800000u) - 1.0f;
    return fmaxf(-1.0f, u * 2.0f - 1.0f);
}

// Dir(u) = sin(2049*pi*u/32768)/sin(pi*u/32768), Dir(0)=2049, period 32768.
__device__ __forceinline__ float dir_val(unsigned u) {
    if (u == 0u) return 2049.f;
    const float PIO = 9.58737992e-05f;
    unsigned y = (2049u * u) & 65535u;
    float sgn = 1.f;
    if (y >= 32768u) { y -= 32768u; sgn = -1.f; }
    unsigned yy = (y > 16384u) ? (32768u - y) : y;
    float sy = sgn * sinf((float)yy * PIO);
    unsigned uu = (u > 16384u) ? (32768u - u) : u;
    float su = sinf((float)uu * PIO);
    return sy / su;
}

// ---------------------------------------------------------------------------
// K1: sequential sim. 64 blocks (b*32+m), 64 threads (d).  [unchanged]
// ---------------------------------------------------------------------------
__global__ void sim_kernel(const float* __restrict__ forces, const float* __restrict__ hmod,
                           const float* __restrict__ home, const float* __restrict__ masses,
                           const float* __restrict__ tensions, const float* __restrict__ gains,
                           const float* __restrict__ mics, float* __restrict__ disp,
                           float* __restrict__ rec) {
    const int bm = blockIdx.x;
    const int m = bm & 31;
    const int d = threadIdx.x;
    const float k = tensions[m * 64 + d] / masses[m];
    const float gain = gains[m];
    const float mic = mics[m * 64 + d];
    const float hd = home[d];
    const size_t rowoff = ((size_t)bm * 64 + d) * 2048;
    const float* fp = forces + rowoff;
    const float* hp = hmod + rowoff;
    float* dpo = disp + rowoff;
    float* rp = rec + (size_t)bm * 2048;
    __shared__ float prod[64][65];
    float pos = 0.f, vel = 0.f;
    for (int t0 = 0; t0 < 2048; t0 += 64) {
        #pragma unroll 4
        for (int ts = 0; ts < 64; ++ts) {
            const int t = t0 + ts;
            const float f = fp[t];
            const float h = hd + hp[t];
            const float dir = h - pos;
            const float acc = f + k * dir;
            vel = (vel + acc) * DAMP;
            pos = pos + vel;
            dpo[t] = dir;
            const float x = vel * gain;
            const float e = __expf(2.f * x);
            const float th = 1.f - 2.f / (e + 1.f);
            prod[ts][d] = th * mic;
        }
        __syncthreads();
        float s = 0.f;
        #pragma unroll
        for (int j = 0; j < 64; ++j) s += prod[d][j];
        rp[t0 + d] = s;
        __syncthreads();
    }
}

// ---------------------------------------------------------------------------
// K2: fft_resample via per-phase circular convolution + abs*noise. [unchanged]
// ---------------------------------------------------------------------------
__global__ __launch_bounds__(512) void resample_kernel(const float* __restrict__ rec,
                                                       float* __restrict__ up) {
    const int bm = blockIdx.x;
    const int p = blockIdx.y;
    const int tid = threadIdx.x;
    __shared__ __align__(16) float rec2[4096];
    __shared__ __align__(16) float dpl[2048];
    for (int i = tid; i < 2048; i += 512) {
        const float v = rec[(size_t)bm * 2048 + i];
        rec2[i] = v; rec2[i + 2048] = v;
        dpl[i] = dir_val(16u * (unsigned)i + (unsigned)p);
    }
    __syncthreads();
    const int qb = tid * 4;
    float a0 = 0.f, a1 = 0.f, a2 = 0.f, a3 = 0.f;
    const float4* f4r = (const float4*)rec2;
    const float4* f4d = (const float4*)dpl;
    for (int v0 = 0; v0 < 2048; v0 += 4) {
        const float4 dv = f4d[v0 >> 2];
        const int base = qb - v0 + 2044;
        const float4 wa = f4r[base >> 2];
        const float4 wb = f4r[(base >> 2) + 1];
        a0 += dv.x * wb.x; a0 += dv.y * wa.w; a0 += dv.z * wa.z; a0 += dv.w * wa.y;
        a1 += dv.x * wb.y; a1 += dv.y * wb.x; a1 += dv.z * wa.w; a1 += dv.w * wa.z;
        a2 += dv.x * wb.z; a2 += dv.y * wb.y; a2 += dv.z * wb.x; a2 += dv.w * wa.w;
        a3 += dv.x * wb.w; a3 += dv.y * wb.z; a3 += dv.z * wb.y; a3 += dv.w * wb.x;
    }
    const float av[4] = {a0, a1, a2, a3};
    const unsigned jbase = (unsigned)bm * 32768u;
    #pragma unroll
    for (int j = 0; j < 4; ++j) {
        const int s = 16 * (qb + j) + p;
        const float v = av[j] * (1.f / 8192.f);
        const float nz = noise_at(jbase + (unsigned)s);
        up[(size_t)bm * 32768 + s] = fabsf(v) * nz;
    }
}

// ---------------------------------------------------------------------------
// K3 (MFMA): hf[bm,s] = up[bm,s] + sum_f mixi[f,s] * FIR(f,s)
// FIR via v_mfma_f32_16x16x32_bf16: D[f][n] = sum_k fr[f][k]*upwin[off+16n+k],
// fr = reversed normalized filter (correlation form). 8 element-shifted bf16
// copies of the up-window fix the 2B misalignment of residue tiles.
// grid (16 s-tiles of 2048, 64 bm), 256 threads (4 waves).
// C/D layout (HW-verified): col=lane&15, row=4*(lane>>4)+reg.
// ---------------------------------------------------------------------------
#define COPY_STRIDE 5120          // bytes per shifted copy (2560 bf16)
#define MIXL_OFF    40960         // 16 x 130 f32
#define NRM_OFF     49280
#define SMEM_BYTES  49344
#define DSPL_OFF    0             // 64 x 130 f32 (aliased, dead before copies)
#define TFL_OFF     33280         // 64 x 16 f32

__global__ __launch_bounds__(256) void hf_kernel(const float* __restrict__ up,
                                                 const float* __restrict__ filters,
                                                 const float* __restrict__ disp,
                                                 const float* __restrict__ tofm,
                                                 float* __restrict__ hf) {
    const int tile = blockIdx.x;     // 0..15
    const int bm = blockIdx.y;       // 0..63
    const int b = bm >> 5;
    const int S0 = tile * 2048;
    const int tbase = tile * 128 - 1;
    const int tid = threadIdx.x;

    __shared__ __align__(16) unsigned char smem[SMEM_BYTES];
    float* dspl = (float*)(smem + DSPL_OFF);
    float* tfl  = (float*)(smem + TFL_OFF);
    float* mixl = (float*)(smem + MIXL_OFF);
    float* nrm  = (float*)(smem + NRM_OFF);

    // ---- phase 0: stage disp window + tofm; compute filter norms ----
    for (int i = tid; i < 1024; i += 256) tfl[i] = tofm[i];
    for (int i = tid; i < 64 * 130; i += 256) {
        const int d = i / 130, tt = i - d * 130;
        const int t = tbase + tt;
        dspl[d * 130 + tt] = (t >= 0 && t < 2048) ? disp[((size_t)bm * 64 + d) * 2048 + t] : 0.f;
    }
    {
        const int f = tid >> 4, l16 = tid & 15;
        const float* frow = filters + ((size_t)b * 16 + f) * 512;
        float part = 0.f;
        for (int l = l16; l < 512; l += 16) { const float v = frow[l]; part += v * v; }
        #pragma unroll
        for (int off = 8; off; off >>= 1) part += __shfl_xor(part, off);
        if (l16 == 0) nrm[f] = 1.f / (sqrtf(part) + 1e-8f);
    }
    __syncthreads();

    // ---- phase 1: mixture window mixl[f][tt] = sum_d dspl[d][tt]*tfl[d][f] ----
    for (int i = tid; i < 16 * 130; i += 256) {
        const int f = i / 130, tt = i - f * 130;
        float s = 0.f;
        #pragma unroll 8
        for (int d = 0; d < 64; ++d) s += dspl[d * 130 + tt] * tfl[d * 16 + f];
        mixl[f * 130 + tt] = s;
    }
    __syncthreads();

    // ---- phase 2: stage 8 shifted bf16 copies of upwin (overwrites dspl/tfl);
    //      concurrently build A-fragments (reversed filter) from global ----
    const int lane = tid & 63;
    const int i15  = lane & 15;
    const int g4   = lane >> 4;

    bf16x8 afr[16];
    {
        const float nf = nrm[i15];
        const float* frow = filters + ((size_t)b * 16 + i15) * 512;
        #pragma unroll
        for (int kk = 0; kk < 16; ++kk) {
            bf16x8 a;
            #pragma unroll
            for (int j = 0; j < 8; ++j) {
                const int lp = 32 * kk + 8 * g4 + j;       // reversed-filter index
                a[j] = (short)f2bf(frow[511 - lp] * nf);
            }
            afr[kk] = a;
        }
    }
    for (int x = tid; x < 2560; x += 256) {
        const int gidx = S0 - 511 + x;
        const float u = (gidx >= 0 && gidx < 32768) ? up[(size_t)bm * 32768 + gidx] : 0.f;
        const unsigned short v = f2bf(u);
        #pragma unroll
        for (int sg = 0; sg < 8; ++sg) {
            const int y = x - sg;
            if (y >= 0) *(unsigned short*)(smem + sg * COPY_STRIDE + 2 * y) = v;
        }
    }
    __syncthreads();

    // ---- phase 3: MFMA main loop ----
    const int wv = tid >> 6;     // 0..3
    for (int rr = 0; rr < 4; ++rr) {
        const int rho = wv * 4 + rr;            // s residue 0..15
        const int sig = rho & 7;
        // byte base: copy sig, elem offset (rho - sig) in {0,8}
        const unsigned baseR = (unsigned)(sig * COPY_STRIDE + 2 * (rho - sig))
                             + 32u * i15 + 16u * g4;
        for (int g = 0; g < 8; ++g) {
            f32x4 acc = {0.f, 0.f, 0.f, 0.f};
            const unsigned tb = baseR + 512u * g;
            #pragma unroll
            for (int kk = 0; kk < 16; ++kk) {
                const bf16x8 bfr = *(const bf16x8*)(smem + tb + 64u * kk);
                acc = __builtin_amdgcn_mfma_f32_16x16x32_bf16(afr[kk], bfr, acc, 0, 0, 0);
            }
            // epilogue: this lane's column is s = sτ + 16*i15, rows f = 4*g4+r
            const int stau = S0 + 256 * g + rho;
            const int s = stau + 16 * i15;
            float posf = ((float)s + 0.5f) * 0.0625f - 0.5f;
            posf = fminf(fmaxf(posf, 0.f), 2047.f);
            const int i0 = (int)posf;
            const float wg = posf - (float)i0;
            const int i1 = min(i0 + 1, 2047);
            const int t0 = i0 - tbase, t1 = i1 - tbase;
            float part = 0.f;
            #pragma unroll
            for (int r = 0; r < 4; ++r) {
                const int f = 4 * g4 + r;
                const float mv = mixl[f * 130 + t0] * (1.f - wg) + mixl[f * 130 + t1] * wg;
                part += mv * acc[r];
            }
            part += __shfl_xor(part, 16);
            part += __shfl_xor(part, 32);
            if (g4 == 0) {
                const int e = 511 + 256 * g + rho + 16 * i15;   // upwin elem (copy 0)
                const float upv = bf2f(*(const unsigned short*)(smem + 2 * e));
                hf[(size_t)bm * 32768 + s] = part + upv;
            }
        }
    }
}

// ---------------------------------------------------------------------------
// Launch
// ---------------------------------------------------------------------------
extern "C" void kernel_launch(void* const* d_in, const int* in_sizes, int n_in,
                              void* d_out, int out_size, void* d_ws, size_t ws_size,
                              hipStream_t stream) {
    const float* forces   = (const float*)d_in[0];
    const float* hmod     = (const float*)d_in[1];
    const float* filters  = (const float*)d_in[2];
    const float* home     = (const float*)d_in[3];
    const float* masses   = (const float*)d_in[4];
    const float* tensions = (const float*)d_in[5];
    const float* gains    = (const float*)d_in[6];
    const float* mics     = (const float*)d_in[7];
    const float* tofm     = (const float*)d_in[8];

    float* out  = (float*)d_out;
    float* rec  = out;                  // 131072
    float* disp = out + 131072;         // 8388608
    float* hf   = out + 8519680;        // 2097152

    float* up = (float*)d_ws;           // 2097152 floats

    sim_kernel<<<64, 64, 0, stream>>>(forces, hmod, home, masses, tensions, gains, mics, disp, rec);
    resample_kernel<<<dim3(64, 16), 512, 0, stream>>>(rec, up);
    hf_kernel<<<dim3(16, 64), 256, 0, stream>>>(up, filters, disp, tofm, hf);
}

// Round 7
// 330.336 us; speedup vs baseline: 6.2822x; 1.9811x over previous
//
#include <hip/hip_runtime.h>
#include <cstdint>
#include <cstddef>

// Problem constants (B=2, M=32, D=64, T=2048, F=16, L=512, S=32768)
#define DAMP 0.9998f

typedef __attribute__((ext_vector_type(8))) short bf16x8;
typedef __attribute__((ext_vector_type(4))) float f32x4;

__device__ __forceinline__ unsigned short f2bf(float x) {
    unsigned u = __float_as_uint(x);
    unsigned r = (u + 0x7FFFu + ((u >> 16) & 1u)) >> 16;   // RNE
    return (unsigned short)r;
}
__device__ __forceinline__ float bf2f(unsigned short v) {
    return __uint_as_float((unsigned)v << 16);
}

// ---------------------------------------------------------------------------
// threefry2x32, JAX partitionable mode. key=(0,1); counter (0, j); o0^o1.
// [verified r4]
// ---------------------------------------------------------------------------
__device__ __forceinline__ void threefry_0j(unsigned j, unsigned& o0, unsigned& o1) {
    unsigned x0 = 0u;
    unsigned x1 = j + 1u;
    const unsigned ks2 = 0x1BD11BDBu;
#define TFR(r) { x0 += x1; x1 = (x1 << (r)) | (x1 >> (32 - (r))); x1 ^= x0; }
    TFR(13) TFR(15) TFR(26) TFR(6)
    x0 += 1u;   x1 += ks2 + 1u;
    TFR(17) TFR(29) TFR(16) TFR(24)
    x0 += ks2;  x1 += 0u + 2u;
    TFR(13) TFR(15) TFR(26) TFR(6)
    /*x0+=0*/   x1 += 1u + 3u;
    TFR(17) TFR(29) TFR(16) TFR(24)
    x0 += 1u;   x1 += ks2 + 4u;
    TFR(13) TFR(15) TFR(26) TFR(6)
    x0 += ks2;  x1 += 0u + 5u;
#undef TFR
    o0 = x0; o1 = x1;
}

__device__ __forceinline__ float noise_at(unsigned j) {
    unsigned o0, o1;
    threefry_0j(j, o0, o1);
    unsigned bits = o0 ^ o1;
    float u = __uint_as_float((bits >> 9) | 0x3F800000u) - 1.0f;
    return fmaxf(-1.0f, u * 2.0f - 1.0f);
}

// Dir(u) = sin(2049*pi*u/32768)/sin(pi*u/32768), Dir(0)=2049, period 32768.
__device__ __forceinline__ float dir_val(unsigned u) {
    if (u == 0u) return 2049.f;
    const float PIO = 9.58737992e-05f;
    unsigned y = (2049u * u) & 65535u;
    float sgn = 1.f;
    if (y >= 32768u) { y -= 32768u; sgn = -1.f; }
    unsigned yy = (y > 16384u) ? (32768u - y) : y;
    float sy = sgn * sinf((float)yy * PIO);
    unsigned uu = (u > 16384u) ? (32768u - u) : u;
    float su = sinf((float)uu * PIO);
    return sy / su;
}

// ---------------------------------------------------------------------------
// K0: DirRev table, bf16: DirRev[p][k] = Dir(16*(2047-k)+p), p<16, k<2048.
// grid 128 x 256.
// ---------------------------------------------------------------------------
__global__ void dirrev_kernel(unsigned short* __restrict__ dirrev) {
    const unsigned i = blockIdx.x * 256 + threadIdx.x;   // p*2048 + k
    const unsigned p = i >> 11, k = i & 2047u;
    dirrev[i] = f2bf(dir_val(16u * (2047u - k) + p));
}

// ---------------------------------------------------------------------------
// K1: sequential sim. 64 blocks (b*32+m), 64 threads (d).  [unchanged]
// ---------------------------------------------------------------------------
__global__ void sim_kernel(const float* __restrict__ forces, const float* __restrict__ hmod,
                           const float* __restrict__ home, const float* __restrict__ masses,
                           const float* __restrict__ tensions, const float* __restrict__ gains,
                           const float* __restrict__ mics, float* __restrict__ disp,
                           float* __restrict__ rec) {
    const int bm = blockIdx.x;
    const int m = bm & 31;
    const int d = threadIdx.x;
    const float k = tensions[m * 64 + d] / masses[m];
    const float gain = gains[m];
    const float mic = mics[m * 64 + d];
    const float hd = home[d];
    const size_t rowoff = ((size_t)bm * 64 + d) * 2048;
    const float* fp = forces + rowoff;
    const float* hp = hmod + rowoff;
    float* dpo = disp + rowoff;
    float* rp = rec + (size_t)bm * 2048;
    __shared__ float prod[64][65];
    float pos = 0.f, vel = 0.f;
    for (int t0 = 0; t0 < 2048; t0 += 64) {
        #pragma unroll 4
        for (int ts = 0; ts < 64; ++ts) {
            const int t = t0 + ts;
            const float f = fp[t];
            const float h = hd + hp[t];
            const float dir = h - pos;
            const float acc = f + k * dir;
            vel = (vel + acc) * DAMP;
            pos = pos + vel;
            dpo[t] = dir;
            const float x = vel * gain;
            const float e = __expf(2.f * x);
            const float th = 1.f - 2.f / (e + 1.f);
            prod[ts][d] = th * mic;
        }
        __syncthreads();
        float s = 0.f;
        #pragma unroll
        for (int j = 0; j < 64; ++j) s += prod[d][j];
        rp[t0 + d] = s;
        __syncthreads();
    }
}

// ---------------------------------------------------------------------------
// K2 (MFMA): fft_resample. Per bm: up0[q,p] = (1/8192) sum_k A[p][k]*B[k][q],
// A = DirRev (bf16, staged LDS), B[k][q] = rec[(q-2047+k) mod 2048] (Hankel,
// 8 shifted bf16 window copies). M=16 p, N=16 q per tile, K=2048.
// grid (64 bm, 4 q-chunks of 512), 256 threads (4 waves, 8 q-tiles each).
// Row strides 4112/5136 (=16 mod 128B) -> conflict-free b128 by construction.
// ---------------------------------------------------------------------------
#define DR_STRIDE 4112u
#define W_STRIDE  5136u
#define W_OFF     65792u          // 16*4112
#define RS_SMEM   106880u         // W_OFF + 8*5136

__global__ __launch_bounds__(256) void resample_kernel(const float* __restrict__ rec,
                                                       const unsigned short* __restrict__ dirrev,
                                                       float* __restrict__ up) {
    const int bm = blockIdx.x;
    const int Q0 = blockIdx.y * 512;
    const int tid = threadIdx.x;
    __shared__ __align__(16) unsigned char smem[RS_SMEM];

    // stage DirRev (16 x 2048 bf16), vectorized 16B
    for (int i = tid; i < 4096; i += 256) {
        const int p = i >> 8, c16 = i & 255;
        *(uint4*)(smem + (unsigned)p * DR_STRIDE + 16u * c16) = ((const uint4*)dirrev)[i];
    }
    // stage window copies: W[x] = rec[(Q0+x+1) & 2047], copy sg: [y] = W[y+sg]
    for (int x = tid; x < 2560; x += 256) {
        const int g = (Q0 + x + 1) & 2047;
        const unsigned short bv = f2bf(rec[(size_t)bm * 2048 + g]);
        #pragma unroll
        for (int sg = 0; sg < 8; ++sg) {
            const int y = x - sg;
            if (y >= 0) *(unsigned short*)(smem + W_OFF + sg * W_STRIDE + 2 * y) = bv;
        }
    }
    __syncthreads();

    const int lane = tid & 63;
    const int wv = tid >> 6;
    const int i15 = lane & 15;
    const int g4 = lane >> 4;

    f32x4 acc[8];
    #pragma unroll
    for (int i = 0; i < 8; ++i) acc[i] = (f32x4){0.f, 0.f, 0.f, 0.f};

    const unsigned abase = (unsigned)i15 * DR_STRIDE + 16u * g4;
    const unsigned bbase = W_OFF + (unsigned)(i15 & 7) * W_STRIDE + 16u * (i15 >> 3) + 16u * g4;

    for (int kkb = 0; kkb < 8; ++kkb) {
        bf16x8 afr[8];
        #pragma unroll
        for (int kj = 0; kj < 8; ++kj)
            afr[kj] = *(const bf16x8*)(smem + abase + 64u * (kkb * 8 + kj));
        #pragma unroll
        for (int qtl = 0; qtl < 8; ++qtl) {
            const int qt = wv * 8 + qtl;
            const unsigned bb = bbase + 32u * qt;
            #pragma unroll
            for (int kj = 0; kj < 8; ++kj) {
                const bf16x8 bfr = *(const bf16x8*)(smem + bb + 64u * (kkb * 8 + kj));
                acc[qtl] = __builtin_amdgcn_mfma_f32_16x16x32_bf16(afr[kj], bfr, acc[qtl], 0, 0, 0);
            }
        }
    }

    // epilogue: lane holds up0[p=4*g4+r][q=Q0+16*qt+i15]; s = 16q+p
    #pragma unroll
    for (int qtl = 0; qtl < 8; ++qtl) {
        const int qt = wv * 8 + qtl;
        const int q = Q0 + 16 * qt + i15;
        const int sbase = 16 * q + 4 * g4;
        const unsigned jb = (unsigned)bm * 32768u + (unsigned)sbase;
        float4 o;
        o.x = fabsf(acc[qtl][0] * (1.f / 8192.f)) * noise_at(jb);
        o.y = fabsf(acc[qtl][1] * (1.f / 8192.f)) * noise_at(jb + 1u);
        o.z = fabsf(acc[qtl][2] * (1.f / 8192.f)) * noise_at(jb + 2u);
        o.w = fabsf(acc[qtl][3] * (1.f / 8192.f)) * noise_at(jb + 3u);
        *(float4*)(up + (size_t)bm * 32768 + sbase) = o;
    }
}

// ---------------------------------------------------------------------------
// K3 (MFMA): hf kernel.  [unchanged from round 6]
// ---------------------------------------------------------------------------
#define COPY_STRIDE 5120
#define MIXL_OFF    40960
#define NRM_OFF     49280
#define SMEM_BYTES  49344
#define DSPL_OFF    0
#define TFL_OFF     33280

__global__ __launch_bounds__(256) void hf_kernel(const float* __restrict__ up,
                                                 const float* __restrict__ filters,
                                                 const float* __restrict__ disp,
                                                 const float* __restrict__ tofm,
                                                 float* __restrict__ hf) {
    const int tile = blockIdx.x;     // 0..15
    const int bm = blockIdx.y;       // 0..63
    const int b = bm >> 5;
    const int S0 = tile * 2048;
    const int tbase = tile * 128 - 1;
    const int tid = threadIdx.x;

    __shared__ __align__(16) unsigned char smem[SMEM_BYTES];
    float* dspl = (float*)(smem + DSPL_OFF);
    float* tfl  = (float*)(smem + TFL_OFF);
    float* mixl = (float*)(smem + MIXL_OFF);
    float* nrm  = (float*)(smem + NRM_OFF);

    // ---- phase 0: stage disp window + tofm; compute filter norms ----
    for (int i = tid; i < 1024; i += 256) tfl[i] = tofm[i];
    for (int i = tid; i < 64 * 130; i += 256) {
        const int d = i / 130, tt = i - d * 130;
        const int t = tbase + tt;
        dspl[d * 130 + tt] = (t >= 0 && t < 2048) ? disp[((size_t)bm * 64 + d) * 2048 + t] : 0.f;
    }
    {
        const int f = tid >> 4, l16 = tid & 15;
        const float* frow = filters + ((size_t)b * 16 + f) * 512;
        float part = 0.f;
        for (int l = l16; l < 512; l += 16) { const float v = frow[l]; part += v * v; }
        #pragma unroll
        for (int off = 8; off; off >>= 1) part += __shfl_xor(part, off);
        if (l16 == 0) nrm[f] = 1.f / (sqrtf(part) + 1e-8f);
    }
    __syncthreads();

    // ---- phase 1: mixture window mixl[f][tt] = sum_d dspl[d][tt]*tfl[d][f] ----
    for (int i = tid; i < 16 * 130; i += 256) {
        const int f = i / 130, tt = i - f * 130;
        float s = 0.f;
        #pragma unroll 8
        for (int d = 0; d < 64; ++d) s += dspl[d * 130 + tt] * tfl[d * 16 + f];
        mixl[f * 130 + tt] = s;
    }
    __syncthreads();

    // ---- phase 2: stage 8 shifted bf16 copies of upwin; build A-fragments ----
    const int lane = tid & 63;
    const int i15  = lane & 15;
    const int g4   = lane >> 4;

    bf16x8 afr[16];
    {
        const float nf = nrm[i15];
        const float* frow = filters + ((size_t)b * 16 + i15) * 512;
        #pragma unroll
        for (int kk = 0; kk < 16; ++kk) {
            bf16x8 a;
            #pragma unroll
            for (int j = 0; j < 8; ++j) {
                const int lp = 32 * kk + 8 * g4 + j;
                a[j] = (short)f2bf(frow[511 - lp] * nf);
            }
            afr[kk] = a;
        }
    }
    for (int x = tid; x < 2560; x += 256) {
        const int gidx = S0 - 511 + x;
        const float u = (gidx >= 0 && gidx < 32768) ? up[(size_t)bm * 32768 + gidx] : 0.f;
        const unsigned short v = f2bf(u);
        #pragma unroll
        for (int sg = 0; sg < 8; ++sg) {
            const int y = x - sg;
            if (y >= 0) *(unsigned short*)(smem + sg * COPY_STRIDE + 2 * y) = v;
        }
    }
    __syncthreads();

    // ---- phase 3: MFMA main loop ----
    const int wv = tid >> 6;
    for (int rr = 0; rr < 4; ++rr) {
        const int rho = wv * 4 + rr;
        const int sig = rho & 7;
        const unsigned baseR = (unsigned)(sig * COPY_STRIDE + 2 * (rho - sig))
                             + 32u * i15 + 16u * g4;
        for (int g = 0; g < 8; ++g) {
            f32x4 acc = {0.f, 0.f, 0.f, 0.f};
            const unsigned tb = baseR + 512u * g;
            #pragma unroll
            for (int kk = 0; kk < 16; ++kk) {
                const bf16x8 bfr = *(const bf16x8*)(smem + tb + 64u * kk);
                acc = __builtin_amdgcn_mfma_f32_16x16x32_bf16(afr[kk], bfr, acc, 0, 0, 0);
            }
            const int stau = S0 + 256 * g + rho;
            const int s = stau + 16 * i15;
            float posf = ((float)s + 0.5f) * 0.0625f - 0.5f;
            posf = fminf(fmaxf(posf, 0.f), 2047.f);
            const int i0 = (int)posf;
            const float wg = posf - (float)i0;
            const int i1 = min(i0 + 1, 2047);
            const int t0 = i0 - tbase, t1 = i1 - tbase;
            float part = 0.f;
            #pragma unroll
            for (int r = 0; r < 4; ++r) {
                const int f = 4 * g4 + r;
                const float mv = mixl[f * 130 + t0] * (1.f - wg) + mixl[f * 130 + t1] * wg;
                part += mv * acc[r];
            }
            part += __shfl_xor(part, 16);
            part += __shfl_xor(part, 32);
            if (g4 == 0) {
                const int e = 511 + 256 * g + rho + 16 * i15;
                const float upv = bf2f(*(const unsigned short*)(smem + 2 * e));
                hf[(size_t)bm * 32768 + s] = part + upv;
            }
        }
    }
}

// ---------------------------------------------------------------------------
// Launch
// ---------------------------------------------------------------------------
extern "C" void kernel_launch(void* const* d_in, const int* in_sizes, int n_in,
                              void* d_out, int out_size, void* d_ws, size_t ws_size,
                              hipStream_t stream) {
    const float* forces   = (const float*)d_in[0];
    const float* hmod     = (const float*)d_in[1];
    const float* filters  = (const float*)d_in[2];
    const float* home     = (const float*)d_in[3];
    const float* masses   = (const float*)d_in[4];
    const float* tensions = (const float*)d_in[5];
    const float* gains    = (const float*)d_in[6];
    const float* mics     = (const float*)d_in[7];
    const float* tofm     = (const float*)d_in[8];

    float* out  = (float*)d_out;
    float* rec  = out;                  // 131072
    float* disp = out + 131072;         // 8388608
    float* hf   = out + 8519680;        // 2097152

    float* up = (float*)d_ws;                                    // 2097152 f32
    unsigned short* dirrev = (unsigned short*)((float*)d_ws + 2097152); // 32768 bf16

    dirrev_kernel<<<128, 256, 0, stream>>>(dirrev);
    sim_kernel<<<64, 64, 0, stream>>>(forces, hmod, home, masses, tensions, gains, mics, disp, rec);
    resample_kernel<<<dim3(64, 4), 256, 0, stream>>>(rec, dirrev, up);
    hf_kernel<<<dim3(16, 64), 256, 0, stream>>>(up, filters, disp, tofm, hf);
}

// Round 8
// 197.968 us; speedup vs baseline: 10.4827x; 1.6686x over previous
//
#include <hip/hip_runtime.h>
#include <cstdint>
#include <cstddef>

// Problem constants (B=2, M=32, D=64, T=2048, F=16, L=512, S=32768)
#define DAMP 0.9998f

typedef __attribute__((ext_vector_type(8))) short bf16x8;
typedef __attribute__((ext_vector_type(4))) float f32x4;

__device__ __forceinline__ unsigned short f2bf(float x) {
    unsigned u = __float_as_uint(x);
    unsigned r = (u + 0x7FFFu + ((u >> 16) & 1u)) >> 16;   // RNE
    return (unsigned short)r;
}
__device__ __forceinline__ float bf2f(unsigned short v) {
    return __uint_as_float((unsigned)v << 16);
}

// ---------------------------------------------------------------------------
// threefry2x32, JAX partitionable mode. key=(0,1); counter (0, j); o0^o1.
// [verified r4]
// ---------------------------------------------------------------------------
__device__ __forceinline__ void threefry_0j(unsigned j, unsigned& o0, unsigned& o1) {
    unsigned x0 = 0u;
    unsigned x1 = j + 1u;
    const unsigned ks2 = 0x1BD11BDBu;
#define TFR(r) { x0 += x1; x1 = (x1 << (r)) | (x1 >> (32 - (r))); x1 ^= x0; }
    TFR(13) TFR(15) TFR(26) TFR(6)
    x0 += 1u;   x1 += ks2 + 1u;
    TFR(17) TFR(29) TFR(16) TFR(24)
    x0 += ks2;  x1 += 0u + 2u;
    TFR(13) TFR(15) TFR(26) TFR(6)
    /*x0+=0*/   x1 += 1u + 3u;
    TFR(17) TFR(29) TFR(16) TFR(24)
    x0 += 1u;   x1 += ks2 + 4u;
    TFR(13) TFR(15) TFR(26) TFR(6)
    x0 += ks2;  x1 += 0u + 5u;
#undef TFR
    o0 = x0; o1 = x1;
}

__device__ __forceinline__ float noise_at(unsigned j) {
    unsigned o0, o1;
    threefry_0j(j, o0, o1);
    unsigned bits = o0 ^ o1;
    float u = __uint_as_float((bits >> 9) | 0x3F800000u) - 1.0f;
    return fmaxf(-1.0f, u * 2.0f - 1.0f);
}

// Dir(u) = sin(2049*pi*u/32768)/sin(pi*u/32768), Dir(0)=2049, period 32768.
__device__ __forceinline__ float dir_val(unsigned u) {
    if (u == 0u) return 2049.f;
    const float PIO = 9.58737992e-05f;
    unsigned y = (2049u * u) & 65535u;
    float sgn = 1.f;
    if (y >= 32768u) { y -= 32768u; sgn = -1.f; }
    unsigned yy = (y > 16384u) ? (32768u - y) : y;
    float sy = sgn * sinf((float)yy * PIO);
    unsigned uu = (u > 16384u) ? (32768u - u) : u;
    float su = sinf((float)uu * PIO);
    return sy / su;
}

// ---------------------------------------------------------------------------
// K0: DirRev table, bf16: DirRev[p][k] = Dir(16*(2047-k)+p). grid 128 x 256.
// ---------------------------------------------------------------------------
__global__ void dirrev_kernel(unsigned short* __restrict__ dirrev) {
    const unsigned i = blockIdx.x * 256 + threadIdx.x;
    const unsigned p = i >> 11, k = i & 2047u;
    dirrev[i] = f2bf(dir_val(16u * (2047u - k) + p));
}

// ---------------------------------------------------------------------------
// K1a: sim pass 1 — per chunk local affine constant w_c (64 steps from 0).
// grid 2048 blocks (bm*32+c), 64 threads (d). Coalesced f/h loads + LDS
// transpose; stages only g = f + k*h (one 16.6KB tile).
// ---------------------------------------------------------------------------
__global__ __launch_bounds__(64) void sim_pass1(const float* __restrict__ forces,
                                                const float* __restrict__ hmod,
                                                const float* __restrict__ home,
                                                const float* __restrict__ masses,
                                                const float* __restrict__ tensions,
                                                float* __restrict__ w) {
    const int blk = blockIdx.x;
    const int bm = blk >> 5, c = blk & 31;
    const int m = bm & 31;
    const int d = threadIdx.x;
    const int t0 = c * 64;
    __shared__ float kv[64];
    __shared__ float hv[64];
    __shared__ __align__(16) float gt[64][65];
    kv[d] = tensions[m * 64 + d] / masses[m];
    hv[d] = home[d];
    __syncthreads();
    for (int i = d; i < 1024; i += 64) {
        const int dd = i >> 4, q = (i & 15) * 4;
        const size_t off = ((size_t)bm * 64 + dd) * 2048 + t0 + q;
        const float4 fv = *(const float4*)(forces + off);
        const float4 hm = *(const float4*)(hmod + off);
        const float kk = kv[dd], hh = hv[dd];
        float4 g;
        g.x = fmaf(kk, hh + hm.x, fv.x);
        g.y = fmaf(kk, hh + hm.y, fv.y);
        g.z = fmaf(kk, hh + hm.z, fv.z);
        g.w = fmaf(kk, hh + hm.w, fv.w);
        *(float4*)&gt[dd][q] = g;
    }
    __syncthreads();
    const float k = kv[d];
    float pos = 0.f, vel = 0.f;
    #pragma unroll 8
    for (int ts = 0; ts < 64; ++ts) {
        const float acc = fmaf(-k, pos, gt[d][ts]);   // g - k*pos
        vel = (vel + acc) * DAMP;
        pos = pos + vel;
    }
    float* wrow = w + (size_t)blk * 128;
    wrow[d] = pos; wrow[64 + d] = vel;
}

// ---------------------------------------------------------------------------
// K1b: sim pass 2 — in-block prefix (A^64 in fp64) then 64-step emit with the
// exact reference step formula. grid 2048 blocks, 64 threads.
// disp written back through the f-tile (in-place, coalesced); rec via
// wave-butterfly reduce (off the recurrence critical path).
// ---------------------------------------------------------------------------
__global__ __launch_bounds__(64) void sim_pass2(const float* __restrict__ forces,
                                                const float* __restrict__ hmod,
                                                const float* __restrict__ home,
                                                const float* __restrict__ masses,
                                                const float* __restrict__ tensions,
                                                const float* __restrict__ gains,
                                                const float* __restrict__ mics,
                                                const float* __restrict__ w,
                                                float* __restrict__ disp,
                                                float* __restrict__ rec) {
    const int blk = blockIdx.x;
    const int bm = blk >> 5, c = blk & 31;
    const int m = bm & 31;
    const int d = threadIdx.x;
    const int t0 = c * 64;
    __shared__ __align__(16) float ft[64][65];
    __shared__ __align__(16) float ht[64][65];
    const float k = tensions[m * 64 + d] / masses[m];
    const float gain = gains[m];
    const float mic = mics[m * 64 + d];
    const float hd = home[d];

    // stage tiles (coalesced)
    for (int i = d; i < 1024; i += 64) {
        const int dd = i >> 4, q = (i & 15) * 4;
        const size_t off = ((size_t)bm * 64 + dd) * 2048 + t0 + q;
        *(float4*)&ft[dd][q] = *(const float4*)(forces + off);
        *(float4*)&ht[dd][q] = *(const float4*)(hmod + off);
    }

    // prefix: s_c = sum_{cc<c} A^64^(c-1-cc) w_cc  (fp64, contractive system)
    double pos_d = 0.0, vel_d = 0.0;
    {
        const double kd = (double)k, cd = (double)DAMP;
        double Ma = 1.0 - cd * kd, Mb = cd, Mc = -cd * kd, Md = cd;
        #pragma unroll
        for (int it = 0; it < 6; ++it) {          // A^(2^6) = A^64
            const double na = Ma * Ma + Mb * Mc;
            const double nb = Ma * Mb + Mb * Md;
            const double nc = Mc * Ma + Md * Mc;
            const double nd = Mc * Mb + Md * Md;
            Ma = na; Mb = nb; Mc = nc; Md = nd;
        }
        const float* wb = w + (size_t)(bm * 32) * 128;
        for (int cc = 0; cc < c; ++cc) {
            const double wp = (double)wb[cc * 128 + d];
            const double wv = (double)wb[cc * 128 + 64 + d];
            const double np = Ma * pos_d + Mb * vel_d + wp;
            const double nv = Mc * pos_d + Md * vel_d + wv;
            pos_d = np; vel_d = nv;
        }
    }
    float pos = (float)pos_d, vel = (float)vel_d;
    __syncthreads();

    // emit loop (exact reference step ops)
    float keep = 0.f;
    for (int ts = 0; ts < 64; ++ts) {
        const float f = ft[d][ts];
        const float h = hd + ht[d][ts];
        const float dir = h - pos;
        const float acc = f + k * dir;
        vel = (vel + acc) * DAMP;
        pos = pos + vel;
        ft[d][ts] = dir;                       // in-place disp tile
        const float x = vel * gain;
        const float e = __expf(2.f * x);
        float sum = (1.f - 2.f / (e + 1.f)) * mic;
        #pragma unroll
        for (int off = 1; off < 64; off <<= 1) sum += __shfl_xor(sum, off);
        keep = (ts == d) ? sum : keep;
    }
    __syncthreads();
    for (int i = d; i < 1024; i += 64) {
        const int dd = i >> 4, q = (i & 15) * 4;
        const size_t off = ((size_t)bm * 64 + dd) * 2048 + t0 + q;
        *(float4*)(disp + off) = *(float4*)&ft[dd][q];
    }
    rec[(size_t)bm * 2048 + t0 + d] = keep;
}

// ---------------------------------------------------------------------------
// K2 (MFMA): fft_resample. [unchanged from round 7]
// ---------------------------------------------------------------------------
#define DR_STRIDE 4112u
#define W_STRIDE  5136u
#define W_OFF     65792u
#define RS_SMEM   106880u

__global__ __launch_bounds__(256) void resample_kernel(const float* __restrict__ rec,
                                                       const unsigned short* __restrict__ dirrev,
                                                       float* __restrict__ up) {
    const int bm = blockIdx.x;
    const int Q0 = blockIdx.y * 512;
    const int tid = threadIdx.x;
    __shared__ __align__(16) unsigned char smem[RS_SMEM];

    for (int i = tid; i < 4096; i += 256) {
        const int p = i >> 8, c16 = i & 255;
        *(uint4*)(smem + (unsigned)p * DR_STRIDE + 16u * c16) = ((const uint4*)dirrev)[i];
    }
    for (int x = tid; x < 2560; x += 256) {
        const int g = (Q0 + x + 1) & 2047;
        const unsigned short bv = f2bf(rec[(size_t)bm * 2048 + g]);
        #pragma unroll
        for (int sg = 0; sg < 8; ++sg) {
            const int y = x - sg;
            if (y >= 0) *(unsigned short*)(smem + W_OFF + sg * W_STRIDE + 2 * y) = bv;
        }
    }
    __syncthreads();

    const int lane = tid & 63;
    const int wv = tid >> 6;
    const int i15 = lane & 15;
    const int g4 = lane >> 4;

    f32x4 acc[8];
    #pragma unroll
    for (int i = 0; i < 8; ++i) acc[i] = (f32x4){0.f, 0.f, 0.f, 0.f};

    const unsigned abase = (unsigned)i15 * DR_STRIDE + 16u * g4;
    const unsigned bbase = W_OFF + (unsigned)(i15 & 7) * W_STRIDE + 16u * (i15 >> 3) + 16u * g4;

    for (int kkb = 0; kkb < 8; ++kkb) {
        bf16x8 afr[8];
        #pragma unroll
        for (int kj = 0; kj < 8; ++kj)
            afr[kj] = *(const bf16x8*)(smem + abase + 64u * (kkb * 8 + kj));
        #pragma unroll
        for (int qtl = 0; qtl < 8; ++qtl) {
            const int qt = wv * 8 + qtl;
            const unsigned bb = bbase + 32u * qt;
            #pragma unroll
            for (int kj = 0; kj < 8; ++kj) {
                const bf16x8 bfr = *(const bf16x8*)(smem + bb + 64u * (kkb * 8 + kj));
                acc[qtl] = __builtin_amdgcn_mfma_f32_16x16x32_bf16(afr[kj], bfr, acc[qtl], 0, 0, 0);
            }
        }
    }

    #pragma unroll
    for (int qtl = 0; qtl < 8; ++qtl) {
        const int qt = wv * 8 + qtl;
        const int q = Q0 + 16 * qt + i15;
        const int sbase = 16 * q + 4 * g4;
        const unsigned jb = (unsigned)bm * 32768u + (unsigned)sbase;
        float4 o;
        o.x = fabsf(acc[qtl][0] * (1.f / 8192.f)) * noise_at(jb);
        o.y = fabsf(acc[qtl][1] * (1.f / 8192.f)) * noise_at(jb + 1u);
        o.z = fabsf(acc[qtl][2] * (1.f / 8192.f)) * noise_at(jb + 2u);
        o.w = fabsf(acc[qtl][3] * (1.f / 8192.f)) * noise_at(jb + 3u);
        *(float4*)(up + (size_t)bm * 32768 + sbase) = o;
    }
}

// ---------------------------------------------------------------------------
// K3 (MFMA): hf kernel.  [unchanged from round 6]
// ---------------------------------------------------------------------------
#define COPY_STRIDE 5120
#define MIXL_OFF    40960
#define NRM_OFF     49280
#define SMEM_BYTES  49344
#define DSPL_OFF    0
#define TFL_OFF     33280

__global__ __launch_bounds__(256) void hf_kernel(const float* __restrict__ up,
                                                 const float* __restrict__ filters,
                                                 const float* __restrict__ disp,
                                                 const float* __restrict__ tofm,
                                                 float* __restrict__ hf) {
    const int tile = blockIdx.x;
    const int bm = blockIdx.y;
    const int b = bm >> 5;
    const int S0 = tile * 2048;
    const int tbase = tile * 128 - 1;
    const int tid = threadIdx.x;

    __shared__ __align__(16) unsigned char smem[SMEM_BYTES];
    float* dspl = (float*)(smem + DSPL_OFF);
    float* tfl  = (float*)(smem + TFL_OFF);
    float* mixl = (float*)(smem + MIXL_OFF);
    float* nrm  = (float*)(smem + NRM_OFF);

    for (int i = tid; i < 1024; i += 256) tfl[i] = tofm[i];
    for (int i = tid; i < 64 * 130; i += 256) {
        const int d = i / 130, tt = i - d * 130;
        const int t = tbase + tt;
        dspl[d * 130 + tt] = (t >= 0 && t < 2048) ? disp[((size_t)bm * 64 + d) * 2048 + t] : 0.f;
    }
    {
        const int f = tid >> 4, l16 = tid & 15;
        const float* frow = filters + ((size_t)b * 16 + f) * 512;
        float part = 0.f;
        for (int l = l16; l < 512; l += 16) { const float v = frow[l]; part += v * v; }
        #pragma unroll
        for (int off = 8; off; off >>= 1) part += __shfl_xor(part, off);
        if (l16 == 0) nrm[f] = 1.f / (sqrtf(part) + 1e-8f);
    }
    __syncthreads();

    for (int i = tid; i < 16 * 130; i += 256) {
        const int f = i / 130, tt = i - f * 130;
        float s = 0.f;
        #pragma unroll 8
        for (int d = 0; d < 64; ++d) s += dspl[d * 130 + tt] * tfl[d * 16 + f];
        mixl[f * 130 + tt] = s;
    }
    __syncthreads();

    const int lane = tid & 63;
    const int i15  = lane & 15;
    const int g4   = lane >> 4;

    bf16x8 afr[16];
    {
        const float nf = nrm[i15];
        const float* frow = filters + ((size_t)b * 16 + i15) * 512;
        #pragma unroll
        for (int kk = 0; kk < 16; ++kk) {
            bf16x8 a;
            #pragma unroll
            for (int j = 0; j < 8; ++j) {
                const int lp = 32 * kk + 8 * g4 + j;
                a[j] = (short)f2bf(frow[511 - lp] * nf);
            }
            afr[kk] = a;
        }
    }
    for (int x = tid; x < 2560; x += 256) {
        const int gidx = S0 - 511 + x;
        const float u = (gidx >= 0 && gidx < 32768) ? up[(size_t)bm * 32768 + gidx] : 0.f;
        const unsigned short v = f2bf(u);
        #pragma unroll
        for (int sg = 0; sg < 8; ++sg) {
            const int y = x - sg;
            if (y >= 0) *(unsigned short*)(smem + sg * COPY_STRIDE + 2 * y) = v;
        }
    }
    __syncthreads();

    const int wv = tid >> 6;
    for (int rr = 0; rr < 4; ++rr) {
        const int rho = wv * 4 + rr;
        const int sig = rho & 7;
        const unsigned baseR = (unsigned)(sig * COPY_STRIDE + 2 * (rho - sig))
                             + 32u * i15 + 16u * g4;
        for (int g = 0; g < 8; ++g) {
            f32x4 acc = {0.f, 0.f, 0.f, 0.f};
            const unsigned tb = baseR + 512u * g;
            #pragma unroll
            for (int kk = 0; kk < 16; ++kk) {
                const bf16x8 bfr = *(const bf16x8*)(smem + tb + 64u * kk);
                acc = __builtin_amdgcn_mfma_f32_16x16x32_bf16(afr[kk], bfr, acc, 0, 0, 0);
            }
            const int stau = S0 + 256 * g + rho;
            const int s = stau + 16 * i15;
            float posf = ((float)s + 0.5f) * 0.0625f - 0.5f;
            posf = fminf(fmaxf(posf, 0.f), 2047.f);
            const int i0 = (int)posf;
            const float wg = posf - (float)i0;
            const int i1 = min(i0 + 1, 2047);
            const int t0 = i0 - tbase, t1 = i1 - tbase;
            float part = 0.f;
            #pragma unroll
            for (int r = 0; r < 4; ++r) {
                const int f = 4 * g4 + r;
                const float mv = mixl[f * 130 + t0] * (1.f - wg) + mixl[f * 130 + t1] * wg;
                part += mv * acc[r];
            }
            part += __shfl_xor(part, 16);
            part += __shfl_xor(part, 32);
            if (g4 == 0) {
                const int e = 511 + 256 * g + rho + 16 * i15;
                const float upv = bf2f(*(const unsigned short*)(smem + 2 * e));
                hf[(size_t)bm * 32768 + s] = part + upv;
            }
        }
    }
}

// ---------------------------------------------------------------------------
// Launch
// ---------------------------------------------------------------------------
extern "C" void kernel_launch(void* const* d_in, const int* in_sizes, int n_in,
                              void* d_out, int out_size, void* d_ws, size_t ws_size,
                              hipStream_t stream) {
    const float* forces   = (const float*)d_in[0];
    const float* hmod     = (const float*)d_in[1];
    const float* filters  = (const float*)d_in[2];
    const float* home     = (const float*)d_in[3];
    const float* masses   = (const float*)d_in[4];
    const float* tensions = (const float*)d_in[5];
    const float* gains    = (const float*)d_in[6];
    const float* mics     = (const float*)d_in[7];
    const float* tofm     = (const float*)d_in[8];

    float* out  = (float*)d_out;
    float* rec  = out;                  // 131072
    float* disp = out + 131072;         // 8388608
    float* hf   = out + 8519680;        // 2097152

    float* up = (float*)d_ws;                                           // 2097152 f32
    unsigned short* dirrev = (unsigned short*)((float*)d_ws + 2097152); // 32768 bf16
    float* w = (float*)d_ws + 2113536;                                  // 262144 f32

    dirrev_kernel<<<128, 256, 0, stream>>>(dirrev);
    sim_pass1<<<2048, 64, 0, stream>>>(forces, hmod, home, masses, tensions, w);
    sim_pass2<<<2048, 64, 0, stream>>>(forces, hmod, home, masses, tensions, gains, mics, w, disp, rec);
    resample_kernel<<<dim3(64, 4), 256, 0, stream>>>(rec, dirrev, up);
    hf_kernel<<<dim3(16, 64), 256, 0, stream>>>(up, filters, disp, tofm, hf);
}

// Round 9
// 153.956 us; speedup vs baseline: 13.4794x; 1.2859x over previous
//
#include <hip/hip_runtime.h>
#include <cstdint>
#include <cstddef>

// Problem constants (B=2, M=32, D=64, T=2048, F=16, L=512, S=32768)
#define DAMP 0.9998f

typedef __attribute__((ext_vector_type(8))) short bf16x8;
typedef __attribute__((ext_vector_type(4))) float f32x4;

__device__ __forceinline__ unsigned short f2bf(float x) {
    unsigned u = __float_as_uint(x);
    unsigned r = (u + 0x7FFFu + ((u >> 16) & 1u)) >> 16;   // RNE
    return (unsigned short)r;
}
__device__ __forceinline__ float bf2f(unsigned short v) {
    return __uint_as_float((unsigned)v << 16);
}

// ---------------------------------------------------------------------------
// threefry2x32, JAX partitionable mode. key=(0,1); counter (0, j); o0^o1.
// [verified r4]
// ---------------------------------------------------------------------------
__device__ __forceinline__ void threefry_0j(unsigned j, unsigned& o0, unsigned& o1) {
    unsigned x0 = 0u;
    unsigned x1 = j + 1u;
    const unsigned ks2 = 0x1BD11BDBu;
#define TFR(r) { x0 += x1; x1 = (x1 << (r)) | (x1 >> (32 - (r))); x1 ^= x0; }
    TFR(13) TFR(15) TFR(26) TFR(6)
    x0 += 1u;   x1 += ks2 + 1u;
    TFR(17) TFR(29) TFR(16) TFR(24)
    x0 += ks2;  x1 += 0u + 2u;
    TFR(13) TFR(15) TFR(26) TFR(6)
    /*x0+=0*/   x1 += 1u + 3u;
    TFR(17) TFR(29) TFR(16) TFR(24)
    x0 += 1u;   x1 += ks2 + 4u;
    TFR(13) TFR(15) TFR(26) TFR(6)
    x0 += ks2;  x1 += 0u + 5u;
#undef TFR
    o0 = x0; o1 = x1;
}

__device__ __forceinline__ float noise_at(unsigned j) {
    unsigned o0, o1;
    threefry_0j(j, o0, o1);
    unsigned bits = o0 ^ o1;
    float u = __uint_as_float((bits >> 9) | 0x3F800000u) - 1.0f;
    return fmaxf(-1.0f, u * 2.0f - 1.0f);
}

// Dir(u) = sin(2049*pi*u/32768)/sin(pi*u/32768), Dir(0)=2049, period 32768.
__device__ __forceinline__ float dir_val(unsigned u) {
    if (u == 0u) return 2049.f;
    const float PIO = 9.58737992e-05f;
    unsigned y = (2049u * u) & 65535u;
    float sgn = 1.f;
    if (y >= 32768u) { y -= 32768u; sgn = -1.f; }
    unsigned yy = (y > 16384u) ? (32768u - y) : y;
    float sy = sgn * sinf((float)yy * PIO);
    unsigned uu = (u > 16384u) ? (32768u - u) : u;
    float su = sinf((float)uu * PIO);
    return sy / su;
}

// ---------------------------------------------------------------------------
// K0a: DirRev table, bf16: DirRev[p][k] = Dir(16*(2047-k)+p). grid 128 x 256.
// ---------------------------------------------------------------------------
__global__ void dirrev_kernel(unsigned short* __restrict__ dirrev) {
    const unsigned i = blockIdx.x * 256 + threadIdx.x;
    const unsigned p = i >> 11, k = i & 2047u;
    dirrev[i] = f2bf(dir_val(16u * (2047u - k) + p));
}

// ---------------------------------------------------------------------------
// K0b: prep — normalized REVERSED filters in bf16: fnrev[row][l] =
// filters[row][511-l] / (||filters[row]|| + 1e-8). grid 32 x 64.
// ---------------------------------------------------------------------------
__global__ void prep_kernel(const float* __restrict__ filters,
                            unsigned short* __restrict__ fnrev) {
    const int row = blockIdx.x;      // b*16+f
    const int tid = threadIdx.x;     // 64
    const float* src = filters + (size_t)row * 512;
    float s = 0.f;
    for (int i = tid; i < 512; i += 64) { const float v = src[i]; s += v * v; }
    #pragma unroll
    for (int off = 32; off; off >>= 1) s += __shfl_xor(s, off);
    const float scale = 1.f / (sqrtf(s) + 1e-8f);
    for (int i = tid; i < 512; i += 64)
        fnrev[(size_t)row * 512 + i] = f2bf(src[511 - i] * scale);
}

// ---------------------------------------------------------------------------
// K1a: sim pass 1 — per chunk local affine constant w_c.  [unchanged r8]
// ---------------------------------------------------------------------------
__global__ __launch_bounds__(64) void sim_pass1(const float* __restrict__ forces,
                                                const float* __restrict__ hmod,
                                                const float* __restrict__ home,
                                                const float* __restrict__ masses,
                                                const float* __restrict__ tensions,
                                                float* __restrict__ w) {
    const int blk = blockIdx.x;
    const int bm = blk >> 5, c = blk & 31;
    const int m = bm & 31;
    const int d = threadIdx.x;
    const int t0 = c * 64;
    __shared__ float kv[64];
    __shared__ float hv[64];
    __shared__ __align__(16) float gt[64][65];
    kv[d] = tensions[m * 64 + d] / masses[m];
    hv[d] = home[d];
    __syncthreads();
    for (int i = d; i < 1024; i += 64) {
        const int dd = i >> 4, q = (i & 15) * 4;
        const size_t off = ((size_t)bm * 64 + dd) * 2048 + t0 + q;
        const float4 fv = *(const float4*)(forces + off);
        const float4 hm = *(const float4*)(hmod + off);
        const float kk = kv[dd], hh = hv[dd];
        float4 g;
        g.x = fmaf(kk, hh + hm.x, fv.x);
        g.y = fmaf(kk, hh + hm.y, fv.y);
        g.z = fmaf(kk, hh + hm.z, fv.z);
        g.w = fmaf(kk, hh + hm.w, fv.w);
        *(float4*)&gt[dd][q] = g;
    }
    __syncthreads();
    const float k = kv[d];
    float pos = 0.f, vel = 0.f;
    #pragma unroll 8
    for (int ts = 0; ts < 64; ++ts) {
        const float acc = fmaf(-k, pos, gt[d][ts]);
        vel = (vel + acc) * DAMP;
        pos = pos + vel;
    }
    float* wrow = w + (size_t)blk * 128;
    wrow[d] = pos; wrow[64 + d] = vel;
}

// ---------------------------------------------------------------------------
// K1b: sim pass 2 — fp64 prefix + 64-step emit.  [unchanged r8]
// ---------------------------------------------------------------------------
__global__ __launch_bounds__(64) void sim_pass2(const float* __restrict__ forces,
                                                const float* __restrict__ hmod,
                                                const float* __restrict__ home,
                                                const float* __restrict__ masses,
                                                const float* __restrict__ tensions,
                                                const float* __restrict__ gains,
                                                const float* __restrict__ mics,
                                                const float* __restrict__ w,
                                                float* __restrict__ disp,
                                                float* __restrict__ rec) {
    const int blk = blockIdx.x;
    const int bm = blk >> 5, c = blk & 31;
    const int m = bm & 31;
    const int d = threadIdx.x;
    const int t0 = c * 64;
    __shared__ __align__(16) float ft[64][65];
    __shared__ __align__(16) float ht[64][65];
    const float k = tensions[m * 64 + d] / masses[m];
    const float gain = gains[m];
    const float mic = mics[m * 64 + d];
    const float hd = home[d];

    for (int i = d; i < 1024; i += 64) {
        const int dd = i >> 4, q = (i & 15) * 4;
        const size_t off = ((size_t)bm * 64 + dd) * 2048 + t0 + q;
        *(float4*)&ft[dd][q] = *(const float4*)(forces + off);
        *(float4*)&ht[dd][q] = *(const float4*)(hmod + off);
    }

    double pos_d = 0.0, vel_d = 0.0;
    {
        const double kd = (double)k, cd = (double)DAMP;
        double Ma = 1.0 - cd * kd, Mb = cd, Mc = -cd * kd, Md = cd;
        #pragma unroll
        for (int it = 0; it < 6; ++it) {
            const double na = Ma * Ma + Mb * Mc;
            const double nb = Ma * Mb + Mb * Md;
            const double nc = Mc * Ma + Md * Mc;
            const double nd = Mc * Mb + Md * Md;
            Ma = na; Mb = nb; Mc = nc; Md = nd;
        }
        const float* wb = w + (size_t)(bm * 32) * 128;
        for (int cc = 0; cc < c; ++cc) {
            const double wp = (double)wb[cc * 128 + d];
            const double wv = (double)wb[cc * 128 + 64 + d];
            const double np = Ma * pos_d + Mb * vel_d + wp;
            const double nv = Mc * pos_d + Md * vel_d + wv;
            pos_d = np; vel_d = nv;
        }
    }
    float pos = (float)pos_d, vel = (float)vel_d;
    __syncthreads();

    float keep = 0.f;
    for (int ts = 0; ts < 64; ++ts) {
        const float f = ft[d][ts];
        const float h = hd + ht[d][ts];
        const float dir = h - pos;
        const float acc = f + k * dir;
        vel = (vel + acc) * DAMP;
        pos = pos + vel;
        ft[d][ts] = dir;
        const float x = vel * gain;
        const float e = __expf(2.f * x);
        float sum = (1.f - 2.f / (e + 1.f)) * mic;
        #pragma unroll
        for (int off = 1; off < 64; off <<= 1) sum += __shfl_xor(sum, off);
        keep = (ts == d) ? sum : keep;
    }
    __syncthreads();
    for (int i = d; i < 1024; i += 64) {
        const int dd = i >> 4, q = (i & 15) * 4;
        const size_t off = ((size_t)bm * 64 + dd) * 2048 + t0 + q;
        *(float4*)(disp + off) = *(float4*)&ft[dd][q];
    }
    rec[(size_t)bm * 2048 + t0 + d] = keep;
}

// ---------------------------------------------------------------------------
// K2: mixture[bm,f,t] = sum_d disp[bm,d,t]*tofm[d,f]  -> bf16.
// grid (8, 64) x 256; coalesced disp loads, fp32 accumulate.
// ---------------------------------------------------------------------------
__global__ __launch_bounds__(256) void mix_kernel(const float* __restrict__ disp,
                                                  const float* __restrict__ tofm,
                                                  unsigned short* __restrict__ mixture) {
    __shared__ __align__(16) float tf[64][16];
    const int tid = threadIdx.x;
    for (int i = tid; i < 1024; i += 256) tf[i >> 4][i & 15] = tofm[i];
    __syncthreads();
    const int bm = blockIdx.y;
    const int t = blockIdx.x * 256 + tid;
    float acc[16];
    #pragma unroll
    for (int f = 0; f < 16; ++f) acc[f] = 0.f;
    for (int d = 0; d < 64; ++d) {
        const float v = disp[((size_t)bm * 64 + d) * 2048 + t];
        const float4* r4 = (const float4*)tf[d];
        const float4 a4 = r4[0], b4 = r4[1], c4 = r4[2], d4 = r4[3];
        acc[0]  += v * a4.x; acc[1]  += v * a4.y; acc[2]  += v * a4.z; acc[3]  += v * a4.w;
        acc[4]  += v * b4.x; acc[5]  += v * b4.y; acc[6]  += v * b4.z; acc[7]  += v * b4.w;
        acc[8]  += v * c4.x; acc[9]  += v * c4.y; acc[10] += v * c4.z; acc[11] += v * c4.w;
        acc[12] += v * d4.x; acc[13] += v * d4.y; acc[14] += v * d4.z; acc[15] += v * d4.w;
    }
    #pragma unroll
    for (int f = 0; f < 16; ++f)
        mixture[((size_t)bm * 16 + f) * 2048 + t] = f2bf(acc[f]);
}

// ---------------------------------------------------------------------------
// K3 (MFMA): fft_resample.  [unchanged r7]
// ---------------------------------------------------------------------------
#define DR_STRIDE 4112u
#define W_STRIDE  5136u
#define W_OFF     65792u
#define RS_SMEM   106880u

__global__ __launch_bounds__(256) void resample_kernel(const float* __restrict__ rec,
                                                       const unsigned short* __restrict__ dirrev,
                                                       float* __restrict__ up) {
    const int bm = blockIdx.x;
    const int Q0 = blockIdx.y * 512;
    const int tid = threadIdx.x;
    __shared__ __align__(16) unsigned char smem[RS_SMEM];

    for (int i = tid; i < 4096; i += 256) {
        const int p = i >> 8, c16 = i & 255;
        *(uint4*)(smem + (unsigned)p * DR_STRIDE + 16u * c16) = ((const uint4*)dirrev)[i];
    }
    for (int x = tid; x < 2560; x += 256) {
        const int g = (Q0 + x + 1) & 2047;
        const unsigned short bv = f2bf(rec[(size_t)bm * 2048 + g]);
        #pragma unroll
        for (int sg = 0; sg < 8; ++sg) {
            const int y = x - sg;
            if (y >= 0) *(unsigned short*)(smem + W_OFF + sg * W_STRIDE + 2 * y) = bv;
        }
    }
    __syncthreads();

    const int lane = tid & 63;
    const int wv = tid >> 6;
    const int i15 = lane & 15;
    const int g4 = lane >> 4;

    f32x4 acc[8];
    #pragma unroll
    for (int i = 0; i < 8; ++i) acc[i] = (f32x4){0.f, 0.f, 0.f, 0.f};

    const unsigned abase = (unsigned)i15 * DR_STRIDE + 16u * g4;
    const unsigned bbase = W_OFF + (unsigned)(i15 & 7) * W_STRIDE + 16u * (i15 >> 3) + 16u * g4;

    for (int kkb = 0; kkb < 8; ++kkb) {
        bf16x8 afr[8];
        #pragma unroll
        for (int kj = 0; kj < 8; ++kj)
            afr[kj] = *(const bf16x8*)(smem + abase + 64u * (kkb * 8 + kj));
        #pragma unroll
        for (int qtl = 0; qtl < 8; ++qtl) {
            const int qt = wv * 8 + qtl;
            const unsigned bb = bbase + 32u * qt;
            #pragma unroll
            for (int kj = 0; kj < 8; ++kj) {
                const bf16x8 bfr = *(const bf16x8*)(smem + bb + 64u * (kkb * 8 + kj));
                acc[qtl] = __builtin_amdgcn_mfma_f32_16x16x32_bf16(afr[kj], bfr, acc[qtl], 0, 0, 0);
            }
        }
    }

    #pragma unroll
    for (int qtl = 0; qtl < 8; ++qtl) {
        const int qt = wv * 8 + qtl;
        const int q = Q0 + 16 * qt + i15;
        const int sbase = 16 * q + 4 * g4;
        const unsigned jb = (unsigned)bm * 32768u + (unsigned)sbase;
        float4 o;
        o.x = fabsf(acc[qtl][0] * (1.f / 8192.f)) * noise_at(jb);
        o.y = fabsf(acc[qtl][1] * (1.f / 8192.f)) * noise_at(jb + 1u);
        o.z = fabsf(acc[qtl][2] * (1.f / 8192.f)) * noise_at(jb + 2u);
        o.w = fabsf(acc[qtl][3] * (1.f / 8192.f)) * noise_at(jb + 3u);
        *(float4*)(up + (size_t)bm * 32768 + sbase) = o;
    }
}

// ---------------------------------------------------------------------------
// K4 (MFMA): hf — lean FIR-only kernel. grid (32 s-tiles of 1024, 64 bm),
// 256 threads. LDS 26.9 KB: 8 shifted bf16 up-window copies + bf16 mixl window.
// A-frags from precomputed fnrev (global, L2). Fragment math verified r6.
// ---------------------------------------------------------------------------
#define W_STR2   3088u            // 1544 bf16, padded (1536 used)
#define MX_OFF   24704u           // 8*3088
#define HF_SMEM  26880u           // + 16*68*2

__global__ __launch_bounds__(256) void hf_kernel(const float* __restrict__ up,
                                                 const unsigned short* __restrict__ fnrev,
                                                 const unsigned short* __restrict__ mixture,
                                                 float* __restrict__ hf) {
    const int tile = blockIdx.x;     // 0..31
    const int bm = blockIdx.y;       // 0..63
    const int b = bm >> 5;
    const int S0 = tile * 1024;
    const int tbase = tile * 64 - 1;
    const int tid = threadIdx.x;

    __shared__ __align__(16) unsigned char smem[HF_SMEM];
    unsigned short* mixl = (unsigned short*)(smem + MX_OFF);

    // stage 8 shifted copies: W[x] = up[S0-511+x], x in [0,1536)
    for (int x = tid; x < 1536; x += 256) {
        const int gidx = S0 - 511 + x;
        const float u = (gidx >= 0 && gidx < 32768) ? up[(size_t)bm * 32768 + gidx] : 0.f;
        const unsigned short v = f2bf(u);
        #pragma unroll
        for (int sg = 0; sg < 8; ++sg) {
            const int y = x - sg;
            if (y >= 0) *(unsigned short*)(smem + sg * W_STR2 + 2 * y) = v;
        }
    }
    // stage mixl window (bf16): 16 f x 66 t
    for (int i = tid; i < 16 * 66; i += 256) {
        const int f = i / 66, tt = i - f * 66;
        const int t = tbase + tt;
        mixl[f * 68 + tt] = (t >= 0 && t < 2048)
            ? mixture[((size_t)bm * 16 + f) * 2048 + t] : (unsigned short)0;
    }
    // A-fragments from fnrev (L2-cached, 16B aligned loads)
    const int lane = tid & 63;
    const int i15 = lane & 15;
    const int g4 = lane >> 4;
    const int wv = tid >> 6;
    bf16x8 afr[16];
    #pragma unroll
    for (int kk = 0; kk < 16; ++kk)
        afr[kk] = *(const bf16x8*)(fnrev + (size_t)(b * 16 + i15) * 512 + 32 * kk + 8 * g4);
    __syncthreads();

    for (int rr = 0; rr < 4; ++rr) {
        const int rho = wv * 4 + rr;            // s residue 0..15
        const int sig = rho & 7;
        const unsigned baseR = (unsigned)sig * W_STR2 + 2u * (rho - sig)
                             + 32u * i15 + 16u * g4;
        #pragma unroll
        for (int g = 0; g < 4; ++g) {
            f32x4 acc = {0.f, 0.f, 0.f, 0.f};
            const unsigned tb = baseR + 512u * g;
            #pragma unroll
            for (int kk = 0; kk < 16; ++kk) {
                const bf16x8 bfr = *(const bf16x8*)(smem + tb + 64u * kk);
                acc = __builtin_amdgcn_mfma_f32_16x16x32_bf16(afr[kk], bfr, acc, 0, 0, 0);
            }
            const int s = S0 + 256 * g + rho + 16 * i15;
            float posf = ((float)s + 0.5f) * 0.0625f - 0.5f;
            posf = fminf(fmaxf(posf, 0.f), 2047.f);
            const int i0 = (int)posf;
            const float wg = posf - (float)i0;
            const int i1 = min(i0 + 1, 2047);
            const int t0 = i0 - tbase, t1 = i1 - tbase;
            float part = 0.f;
            #pragma unroll
            for (int r = 0; r < 4; ++r) {
                const int f = 4 * g4 + r;
                const float mv = bf2f(mixl[f * 68 + t0]) * (1.f - wg)
                               + bf2f(mixl[f * 68 + t1]) * wg;
                part += mv * acc[r];
            }
            part += __shfl_xor(part, 16);
            part += __shfl_xor(part, 32);
            if (g4 == 0) {
                const int e = 511 + 256 * g + rho + 16 * i15;   // copy-0 element
                const float upv = bf2f(*(const unsigned short*)(smem + 2 * e));
                hf[(size_t)bm * 32768 + s] = part + upv;
            }
        }
    }
}

// ---------------------------------------------------------------------------
// Launch
// ---------------------------------------------------------------------------
extern "C" void kernel_launch(void* const* d_in, const int* in_sizes, int n_in,
                              void* d_out, int out_size, void* d_ws, size_t ws_size,
                              hipStream_t stream) {
    const float* forces   = (const float*)d_in[0];
    const float* hmod     = (const float*)d_in[1];
    const float* filters  = (const float*)d_in[2];
    const float* home     = (const float*)d_in[3];
    const float* masses   = (const float*)d_in[4];
    const float* tensions = (const float*)d_in[5];
    const float* gains    = (const float*)d_in[6];
    const float* mics     = (const float*)d_in[7];
    const float* tofm     = (const float*)d_in[8];

    float* out  = (float*)d_out;
    float* rec  = out;                  // 131072
    float* disp = out + 131072;         // 8388608
    float* hf   = out + 8519680;        // 2097152

    float* up               = (float*)d_ws;                             // 2097152 f32
    unsigned short* mixture = (unsigned short*)((float*)d_ws + 2097152);// 2097152 bf16
    unsigned short* dirrev  = (unsigned short*)((float*)d_ws + 3145728);// 32768 bf16
    float* w                = (float*)d_ws + 3162112;                   // 262144 f32
    unsigned short* fnrev   = (unsigned short*)((float*)d_ws + 3424256);// 16384 bf16
    // total ws use ~13.7 MB

    dirrev_kernel<<<128, 256, 0, stream>>>(dirrev);
    prep_kernel<<<32, 64, 0, stream>>>(filters, fnrev);
    sim_pass1<<<2048, 64, 0, stream>>>(forces, hmod, home, masses, tensions, w);
    sim_pass2<<<2048, 64, 0, stream>>>(forces, hmod, home, masses, tensions, gains, mics, w, disp, rec);
    mix_kernel<<<dim3(8, 64), 256, 0, stream>>>(disp, tofm, mixture);
    resample_kernel<<<dim3(64, 4), 256, 0, stream>>>(rec, dirrev, up);
    hf_kernel<<<dim3(32, 64), 256, 0, stream>>>(up, fnrev, mixture, hf);
}

// Round 10
// 133.904 us; speedup vs baseline: 15.4979x; 1.1497x over previous
//
#include <hip/hip_runtime.h>
#include <cstdint>
#include <cstddef>

// Problem constants (B=2, M=32, D=64, T=2048, F=16, L=512, S=32768)
#define DAMP 0.9998f

typedef __attribute__((ext_vector_type(8))) short bf16x8;
typedef __attribute__((ext_vector_type(4))) float f32x4;

__device__ __forceinline__ unsigned short f2bf(float x) {
    unsigned u = __float_as_uint(x);
    unsigned r = (u + 0x7FFFu + ((u >> 16) & 1u)) >> 16;   // RNE
    return (unsigned short)r;
}
__device__ __forceinline__ float bf2f(unsigned short v) {
    return __uint_as_float((unsigned)v << 16);
}

// ---------------------------------------------------------------------------
// threefry2x32, JAX partitionable mode. key=(0,1); counter (0, j); o0^o1.
// [verified r4]
// ---------------------------------------------------------------------------
__device__ __forceinline__ void threefry_0j(unsigned j, unsigned& o0, unsigned& o1) {
    unsigned x0 = 0u;
    unsigned x1 = j + 1u;
    const unsigned ks2 = 0x1BD11BDBu;
#define TFR(r) { x0 += x1; x1 = (x1 << (r)) | (x1 >> (32 - (r))); x1 ^= x0; }
    TFR(13) TFR(15) TFR(26) TFR(6)
    x0 += 1u;   x1 += ks2 + 1u;
    TFR(17) TFR(29) TFR(16) TFR(24)
    x0 += ks2;  x1 += 0u + 2u;
    TFR(13) TFR(15) TFR(26) TFR(6)
    /*x0+=0*/   x1 += 1u + 3u;
    TFR(17) TFR(29) TFR(16) TFR(24)
    x0 += 1u;   x1 += ks2 + 4u;
    TFR(13) TFR(15) TFR(26) TFR(6)
    x0 += ks2;  x1 += 0u + 5u;
#undef TFR
    o0 = x0; o1 = x1;
}

__device__ __forceinline__ float noise_at(unsigned j) {
    unsigned o0, o1;
    threefry_0j(j, o0, o1);
    unsigned bits = o0 ^ o1;
    float u = __uint_as_float((bits >> 9) | 0x3F800000u) - 1.0f;
    return fmaxf(-1.0f, u * 2.0f - 1.0f);
}

// Dir(u) = sin(2049*pi*u/32768)/sin(pi*u/32768), Dir(0)=2049, period 32768.
__device__ __forceinline__ float dir_val(unsigned u) {
    if (u == 0u) return 2049.f;
    const float PIO = 9.58737992e-05f;
    unsigned y = (2049u * u) & 65535u;
    float sgn = 1.f;
    if (y >= 32768u) { y -= 32768u; sgn = -1.f; }
    unsigned yy = (y > 16384u) ? (32768u - y) : y;
    float sy = sgn * sinf((float)yy * PIO);
    unsigned uu = (u > 16384u) ? (32768u - u) : u;
    float su = sinf((float)uu * PIO);
    return sy / su;
}

// ---------------------------------------------------------------------------
// K0a: DirRev table, bf16. [unchanged]
// ---------------------------------------------------------------------------
__global__ void dirrev_kernel(unsigned short* __restrict__ dirrev) {
    const unsigned i = blockIdx.x * 256 + threadIdx.x;
    const unsigned p = i >> 11, k = i & 2047u;
    dirrev[i] = f2bf(dir_val(16u * (2047u - k) + p));
}

// ---------------------------------------------------------------------------
// K0b: prep — normalized reversed filters, bf16. [unchanged]
// ---------------------------------------------------------------------------
__global__ void prep_kernel(const float* __restrict__ filters,
                            unsigned short* __restrict__ fnrev) {
    const int row = blockIdx.x;
    const int tid = threadIdx.x;
    const float* src = filters + (size_t)row * 512;
    float s = 0.f;
    for (int i = tid; i < 512; i += 64) { const float v = src[i]; s += v * v; }
    #pragma unroll
    for (int off = 32; off; off >>= 1) s += __shfl_xor(s, off);
    const float scale = 1.f / (sqrtf(s) + 1e-8f);
    for (int i = tid; i < 512; i += 64)
        fnrev[(size_t)row * 512 + i] = f2bf(src[511 - i] * scale);
}

// ---------------------------------------------------------------------------
// K1a: sim pass 1 — 32-step chunk local affine constant w_c (from zero state).
// grid 4096 (bm*64+c), 64 threads. g-tile [64][33] = 8.4 KB.
// ---------------------------------------------------------------------------
__global__ __launch_bounds__(64) void sim_pass1(const float* __restrict__ forces,
                                                const float* __restrict__ hmod,
                                                const float* __restrict__ home,
                                                const float* __restrict__ masses,
                                                const float* __restrict__ tensions,
                                                float* __restrict__ w) {
    const int blk = blockIdx.x;
    const int bm = blk >> 6, c = blk & 63;
    const int m = bm & 31;
    const int d = threadIdx.x;
    const int t0 = c * 32;
    __shared__ float kv[64];
    __shared__ float hv[64];
    __shared__ __align__(16) float gt[64][33];
    kv[d] = tensions[m * 64 + d] / masses[m];
    hv[d] = home[d];
    __syncthreads();
    for (int i = d; i < 512; i += 64) {
        const int dd = i >> 3, q = (i & 7) * 4;
        const size_t off = ((size_t)bm * 64 + dd) * 2048 + t0 + q;
        const float4 fv = *(const float4*)(forces + off);
        const float4 hm = *(const float4*)(hmod + off);
        const float kk = kv[dd], hh = hv[dd];
        float4 g;
        g.x = fmaf(kk, hh + hm.x, fv.x);
        g.y = fmaf(kk, hh + hm.y, fv.y);
        g.z = fmaf(kk, hh + hm.z, fv.z);
        g.w = fmaf(kk, hh + hm.w, fv.w);
        *(float4*)&gt[dd][q] = g;
    }
    __syncthreads();
    const float k = kv[d];
    float pos = 0.f, vel = 0.f;
    #pragma unroll 8
    for (int ts = 0; ts < 32; ++ts) {
        const float acc = fmaf(-k, pos, gt[d][ts]);
        vel = (vel + acc) * DAMP;
        pos = pos + vel;
    }
    float* wrow = w + (size_t)blk * 128;
    wrow[d] = pos; wrow[64 + d] = vel;
}

// ---------------------------------------------------------------------------
// K1b: sim scan — fp64 A^32, serial scan over 64 chunks per (bm,d).
// IN PLACE: reads w[c], overwrites the slot with the chunk-ENTRY state.
// grid 64 (bm), 64 threads (d).
// ---------------------------------------------------------------------------
__global__ __launch_bounds__(64) void sim_scan(const float* __restrict__ masses,
                                               const float* __restrict__ tensions,
                                               float* __restrict__ w) {
    const int bm = blockIdx.x;
    const int m = bm & 31;
    const int d = threadIdx.x;
    const double kd = (double)(tensions[m * 64 + d] / masses[m]);
    const double cd = (double)DAMP;
    double Ma = 1.0 - cd * kd, Mb = cd, Mc = -cd * kd, Md = cd;
    #pragma unroll
    for (int it = 0; it < 5; ++it) {             // A^(2^5) = A^32
        const double na = Ma * Ma + Mb * Mc;
        const double nb = Ma * Mb + Mb * Md;
        const double nc = Mc * Ma + Md * Mc;
        const double nd = Mc * Mb + Md * Md;
        Ma = na; Mb = nb; Mc = nc; Md = nd;
    }
    double pos = 0.0, vel = 0.0;
    float* wb = w + (size_t)bm * 64 * 128;
    for (int c = 0; c < 64; ++c) {
        float* row = wb + c * 128;
        const double wp = (double)row[d];
        const double wv = (double)row[64 + d];
        row[d] = (float)pos;                     // entry state of chunk c
        row[64 + d] = (float)vel;
        const double np = Ma * pos + Mb * vel + wp;
        const double nv = Mc * pos + Md * vel + wv;
        pos = np; vel = nv;
    }
}

// ---------------------------------------------------------------------------
// K1c: sim pass 2 — 32-step emit from precomputed entry state, two 16-ts
// quarter stages. LDS 8.9 KB. dir overwrites f-tile (disp), tanh*mic
// overwrites h-tile (rec reduce: 16 LDS reads + 2 shfl per thread).
// grid 4096 (bm*64+c), 64 threads.
// ---------------------------------------------------------------------------
__global__ __launch_bounds__(64) void sim_pass2(const float* __restrict__ forces,
                                                const float* __restrict__ hmod,
                                                const float* __restrict__ home,
                                                const float* __restrict__ masses,
                                                const float* __restrict__ tensions,
                                                const float* __restrict__ gains,
                                                const float* __restrict__ mics,
                                                const float* __restrict__ w,
                                                float* __restrict__ disp,
                                                float* __restrict__ rec) {
    const int blk = blockIdx.x;
    const int bm = blk >> 6, c = blk & 63;
    const int m = bm & 31;
    const int d = threadIdx.x;
    const int t0 = c * 32;
    __shared__ __align__(16) float ft[64][17];
    __shared__ __align__(16) float ht[64][17];
    const float k = tensions[m * 64 + d] / masses[m];
    const float gain = gains[m];
    const float mic = mics[m * 64 + d];
    const float hd = home[d];

    float pos = w[(size_t)blk * 128 + d];
    float vel = w[(size_t)blk * 128 + 64 + d];

    #pragma unroll
    for (int phase = 0; phase < 2; ++phase) {
        const int t0p = t0 + phase * 16;
        for (int i = d; i < 256; i += 64) {
            const int dd = i >> 2, q = (i & 3) * 4;
            const size_t off = ((size_t)bm * 64 + dd) * 2048 + t0p + q;
            *(float4*)&ft[dd][q] = *(const float4*)(forces + off);
            *(float4*)&ht[dd][q] = *(const float4*)(hmod + off);
        }
        __syncthreads();
        #pragma unroll
        for (int ts = 0; ts < 16; ++ts) {
            const float f = ft[d][ts];
            const float h = hd + ht[d][ts];
            const float dir = h - pos;
            const float acc = f + k * dir;
            vel = (vel + acc) * DAMP;
            pos = pos + vel;
            ft[d][ts] = dir;                        // disp tile (in place)
            const float x = vel * gain;
            const float e = __expf(2.f * x);
            ht[d][ts] = (1.f - 2.f / (e + 1.f)) * mic;   // prod tile (in place)
        }
        __syncthreads();
        for (int i = d; i < 256; i += 64) {
            const int dd = i >> 2, q = (i & 3) * 4;
            const size_t off = ((size_t)bm * 64 + dd) * 2048 + t0p + q;
            *(float4*)(disp + off) = *(float4*)&ft[dd][q];
        }
        // rec: thread d -> (ts = d&15, part = d>>4); sum 16 d-rows, combine
        {
            const int ts = d & 15, part = d >> 4;
            float s = 0.f;
            #pragma unroll
            for (int j = 0; j < 16; ++j) s += ht[16 * part + j][ts];
            s += __shfl_xor(s, 16);
            s += __shfl_xor(s, 32);
            if (d < 16) rec[(size_t)bm * 2048 + t0p + d] = s;
        }
        __syncthreads();
    }
}

// ---------------------------------------------------------------------------
// K2: mixture (fp32 acc -> bf16). [unchanged r9]
// ---------------------------------------------------------------------------
__global__ __launch_bounds__(256) void mix_kernel(const float* __restrict__ disp,
                                                  const float* __restrict__ tofm,
                                                  unsigned short* __restrict__ mixture) {
    __shared__ __align__(16) float tf[64][16];
    const int tid = threadIdx.x;
    for (int i = tid; i < 1024; i += 256) tf[i >> 4][i & 15] = tofm[i];
    __syncthreads();
    const int bm = blockIdx.y;
    const int t = blockIdx.x * 256 + tid;
    float acc[16];
    #pragma unroll
    for (int f = 0; f < 16; ++f) acc[f] = 0.f;
    for (int d = 0; d < 64; ++d) {
        const float v = disp[((size_t)bm * 64 + d) * 2048 + t];
        const float4* r4 = (const float4*)tf[d];
        const float4 a4 = r4[0], b4 = r4[1], c4 = r4[2], d4 = r4[3];
        acc[0]  += v * a4.x; acc[1]  += v * a4.y; acc[2]  += v * a4.z; acc[3]  += v * a4.w;
        acc[4]  += v * b4.x; acc[5]  += v * b4.y; acc[6]  += v * b4.z; acc[7]  += v * b4.w;
        acc[8]  += v * c4.x; acc[9]  += v * c4.y; acc[10] += v * c4.z; acc[11] += v * c4.w;
        acc[12] += v * d4.x; acc[13] += v * d4.y; acc[14] += v * d4.z; acc[15] += v * d4.w;
    }
    #pragma unroll
    for (int f = 0; f < 16; ++f)
        mixture[((size_t)bm * 16 + f) * 2048 + t] = f2bf(acc[f]);
}

// ---------------------------------------------------------------------------
// K3 (MFMA): fft_resample. [unchanged r7]
// ---------------------------------------------------------------------------
#define DR_STRIDE 4112u
#define W_STRIDE  5136u
#define W_OFF     65792u
#define RS_SMEM   106880u

__global__ __launch_bounds__(256) void resample_kernel(const float* __restrict__ rec,
                                                       const unsigned short* __restrict__ dirrev,
                                                       float* __restrict__ up) {
    const int bm = blockIdx.x;
    const int Q0 = blockIdx.y * 512;
    const int tid = threadIdx.x;
    __shared__ __align__(16) unsigned char smem[RS_SMEM];

    for (int i = tid; i < 4096; i += 256) {
        const int p = i >> 8, c16 = i & 255;
        *(uint4*)(smem + (unsigned)p * DR_STRIDE + 16u * c16) = ((const uint4*)dirrev)[i];
    }
    for (int x = tid; x < 2560; x += 256) {
        const int g = (Q0 + x + 1) & 2047;
        const unsigned short bv = f2bf(rec[(size_t)bm * 2048 + g]);
        #pragma unroll
        for (int sg = 0; sg < 8; ++sg) {
            const int y = x - sg;
            if (y >= 0) *(unsigned short*)(smem + W_OFF + sg * W_STRIDE + 2 * y) = bv;
        }
    }
    __syncthreads();

    const int lane = tid & 63;
    const int wv = tid >> 6;
    const int i15 = lane & 15;
    const int g4 = lane >> 4;

    f32x4 acc[8];
    #pragma unroll
    for (int i = 0; i < 8; ++i) acc[i] = (f32x4){0.f, 0.f, 0.f, 0.f};

    const unsigned abase = (unsigned)i15 * DR_STRIDE + 16u * g4;
    const unsigned bbase = W_OFF + (unsigned)(i15 & 7) * W_STRIDE + 16u * (i15 >> 3) + 16u * g4;

    for (int kkb = 0; kkb < 8; ++kkb) {
        bf16x8 afr[8];
        #pragma unroll
        for (int kj = 0; kj < 8; ++kj)
            afr[kj] = *(const bf16x8*)(smem + abase + 64u * (kkb * 8 + kj));
        #pragma unroll
        for (int qtl = 0; qtl < 8; ++qtl) {
            const int qt = wv * 8 + qtl;
            const unsigned bb = bbase + 32u * qt;
            #pragma unroll
            for (int kj = 0; kj < 8; ++kj) {
                const bf16x8 bfr = *(const bf16x8*)(smem + bb + 64u * (kkb * 8 + kj));
                acc[qtl] = __builtin_amdgcn_mfma_f32_16x16x32_bf16(afr[kj], bfr, acc[qtl], 0, 0, 0);
            }
        }
    }

    #pragma unroll
    for (int qtl = 0; qtl < 8; ++qtl) {
        const int qt = wv * 8 + qtl;
        const int q = Q0 + 16 * qt + i15;
        const int sbase = 16 * q + 4 * g4;
        const unsigned jb = (unsigned)bm * 32768u + (unsigned)sbase;
        float4 o;
        o.x = fabsf(acc[qtl][0] * (1.f / 8192.f)) * noise_at(jb);
        o.y = fabsf(acc[qtl][1] * (1.f / 8192.f)) * noise_at(jb + 1u);
        o.z = fabsf(acc[qtl][2] * (1.f / 8192.f)) * noise_at(jb + 2u);
        o.w = fabsf(acc[qtl][3] * (1.f / 8192.f)) * noise_at(jb + 3u);
        *(float4*)(up + (size_t)bm * 32768 + sbase) = o;
    }
}

// ---------------------------------------------------------------------------
// K4 (MFMA): hf. [unchanged r9]
// ---------------------------------------------------------------------------
#define W_STR2   3088u
#define MX_OFF   24704u
#define HF_SMEM  26880u

__global__ __launch_bounds__(256) void hf_kernel(const float* __restrict__ up,
                                                 const unsigned short* __restrict__ fnrev,
                                                 const unsigned short* __restrict__ mixture,
                                                 float* __restrict__ hf) {
    const int tile = blockIdx.x;
    const int bm = blockIdx.y;
    const int b = bm >> 5;
    const int S0 = tile * 1024;
    const int tbase = tile * 64 - 1;
    const int tid = threadIdx.x;

    __shared__ __align__(16) unsigned char smem[HF_SMEM];
    unsigned short* mixl = (unsigned short*)(smem + MX_OFF);

    for (int x = tid; x < 1536; x += 256) {
        const int gidx = S0 - 511 + x;
        const float u = (gidx >= 0 && gidx < 32768) ? up[(size_t)bm * 32768 + gidx] : 0.f;
        const unsigned short v = f2bf(u);
        #pragma unroll
        for (int sg = 0; sg < 8; ++sg) {
            const int y = x - sg;
            if (y >= 0) *(unsigned short*)(smem + sg * W_STR2 + 2 * y) = v;
        }
    }
    for (int i = tid; i < 16 * 66; i += 256) {
        const int f = i / 66, tt = i - f * 66;
        const int t = tbase + tt;
        mixl[f * 68 + tt] = (t >= 0 && t < 2048)
            ? mixture[((size_t)bm * 16 + f) * 2048 + t] : (unsigned short)0;
    }
    const int lane = tid & 63;
    const int i15 = lane & 15;
    const int g4 = lane >> 4;
    const int wv = tid >> 6;
    bf16x8 afr[16];
    #pragma unroll
    for (int kk = 0; kk < 16; ++kk)
        afr[kk] = *(const bf16x8*)(fnrev + (size_t)(b * 16 + i15) * 512 + 32 * kk + 8 * g4);
    __syncthreads();

    for (int rr = 0; rr < 4; ++rr) {
        const int rho = wv * 4 + rr;
        const int sig = rho & 7;
        const unsigned baseR = (unsigned)sig * W_STR2 + 2u * (rho - sig)
                             + 32u * i15 + 16u * g4;
        #pragma unroll
        for (int g = 0; g < 4; ++g) {
            f32x4 acc = {0.f, 0.f, 0.f, 0.f};
            const unsigned tb = baseR + 512u * g;
            #pragma unroll
            for (int kk = 0; kk < 16; ++kk) {
                const bf16x8 bfr = *(const bf16x8*)(smem + tb + 64u * kk);
                acc = __builtin_amdgcn_mfma_f32_16x16x32_bf16(afr[kk], bfr, acc, 0, 0, 0);
            }
            const int s = S0 + 256 * g + rho + 16 * i15;
            float posf = ((float)s + 0.5f) * 0.0625f - 0.5f;
            posf = fminf(fmaxf(posf, 0.f), 2047.f);
            const int i0 = (int)posf;
            const float wg = posf - (float)i0;
            const int i1 = min(i0 + 1, 2047);
            const int t0 = i0 - tbase, t1 = i1 - tbase;
            float part = 0.f;
            #pragma unroll
            for (int r = 0; r < 4; ++r) {
                const int f = 4 * g4 + r;
                const float mv = bf2f(mixl[f * 68 + t0]) * (1.f - wg)
                               + bf2f(mixl[f * 68 + t1]) * wg;
                part += mv * acc[r];
            }
            part += __shfl_xor(part, 16);
            part += __shfl_xor(part, 32);
            if (g4 == 0) {
                const int e = 511 + 256 * g + rho + 16 * i15;
                const float upv = bf2f(*(const unsigned short*)(smem + 2 * e));
                hf[(size_t)bm * 32768 + s] = part + upv;
            }
        }
    }
}

// ---------------------------------------------------------------------------
// Launch
// ---------------------------------------------------------------------------
extern "C" void kernel_launch(void* const* d_in, const int* in_sizes, int n_in,
                              void* d_out, int out_size, void* d_ws, size_t ws_size,
                              hipStream_t stream) {
    const float* forces   = (const float*)d_in[0];
    const float* hmod     = (const float*)d_in[1];
    const float* filters  = (const float*)d_in[2];
    const float* home     = (const float*)d_in[3];
    const float* masses   = (const float*)d_in[4];
    const float* tensions = (const float*)d_in[5];
    const float* gains    = (const float*)d_in[6];
    const float* mics     = (const float*)d_in[7];
    const float* tofm     = (const float*)d_in[8];

    float* out  = (float*)d_out;
    float* rec  = out;                  // 131072
    float* disp = out + 131072;         // 8388608
    float* hf   = out + 8519680;        // 2097152

    float* up               = (float*)d_ws;                             // 2097152 f32
    unsigned short* mixture = (unsigned short*)((float*)d_ws + 2097152);// 2097152 bf16
    unsigned short* dirrev  = (unsigned short*)((float*)d_ws + 3145728);// 32768 bf16
    float* w                = (float*)d_ws + 3162112;                   // 524288 f32
    unsigned short* fnrev   = (unsigned short*)((float*)d_ws + 3686400);// 16384 bf16
    // total ws use ~14.8 MB

    dirrev_kernel<<<128, 256, 0, stream>>>(dirrev);
    prep_kernel<<<32, 64, 0, stream>>>(filters, fnrev);
    sim_pass1<<<4096, 64, 0, stream>>>(forces, hmod, home, masses, tensions, w);
    sim_scan<<<64, 64, 0, stream>>>(masses, tensions, w);
    sim_pass2<<<4096, 64, 0, stream>>>(forces, hmod, home, masses, tensions, gains, mics, w, disp, rec);
    mix_kernel<<<dim3(8, 64), 256, 0, stream>>>(disp, tofm, mixture);
    resample_kernel<<<dim3(64, 4), 256, 0, stream>>>(rec, dirrev, up);
    hf_kernel<<<dim3(32, 64), 256, 0, stream>>>(up, fnrev, mixture, hf);
}